// Round 5
// baseline (186.341 us; speedup 1.0000x reference)
//
#include <hip/hip_runtime.h>

// ---------------------------------------------------------------------------
// StandardMultiHeadAttention: B=2, S=2048, D=1024, H=16, Dh=64, causal.
// fp32->f16 convert (single kernel) -> QKV GEMM (BK=64, frag-major epilogue)
// -> flash attention (LDS-shared KV, 64-row q-blocks) -> output GEMM.
//
// Workspace (48 MB):
//   [0,8M)    xb : x f16 [4096,1024]
//   [8M,16M)  wb : Wq,Wk,Wv,Wo f16 (row=out, K-major)
//   [16M,24M) QF : Q frag-major (pre-scaled by 0.125*log2e)
//   [24M,32M) KF : K frag-major (tile-contiguous: tile t = [t*2048,+2048) halfs)
//   [32M,40M) VF : V^T frag-major (same tiling)
//   [40M,48M) ob : attention output [B,S,1024] f16
//
// R17 post-mortem of R16: occupancy doubled (24->49%) exactly as designed,
// time unchanged (43us), VALUBusy FELL 32->24 -> a saturated shared pipe,
// not wave starvation. The uncounted pipe is vector-memory/L1: K,V loaded
// straight to registers = 66,560 tile instances x 8KB x 2 (h-dup) = 1.09 GB
// = 4.26 MB/CU ~ 66k cyc/CU at ~64 B/cyc ~ 27us of the 43. R13/R15/R16 all
// tied at 43us because none changed VMEM bytes.
// R17: stage each 32-row KV tile into LDS ONCE per 64-row q-block (4 waves
// x 16 rows share it) -> VMEM /4 (277 MB). Double-buffered staging with
// counted-vmcnt raw-barrier pipeline (stage t+1 -> vmcnt(2) -> s_barrier ->
// compute t -> s_barrier): prefetch stays in flight across barriers (no
// __syncthreads vmcnt(0) drain). No merge (waves own complete q-rows).
// LDS 24KB/block -> 6 blocks/CU; launch_bounds(256,6). Longest-first
// dispatch; bh = i&31 keeps 4 heads/XCD (2MB KV) L2-resident.
// ---------------------------------------------------------------------------

typedef _Float16 f16x8 __attribute__((ext_vector_type(8)));
typedef _Float16 f16x4 __attribute__((ext_vector_type(4)));
typedef _Float16 f16x2 __attribute__((ext_vector_type(2)));
typedef float f32x4 __attribute__((ext_vector_type(4)));

#define S_  2048
#define DM  1024
#define NH  16
#define DH  64

__device__ __forceinline__ void gload_lds16(const void* g, void* s) {
  __builtin_amdgcn_global_load_lds(
      (const __attribute__((address_space(1))) void*)g,
      (__attribute__((address_space(3))) void*)s, 16, 0, 0);
}

__device__ __forceinline__ f16x2 pkrtz(float a, float b) {
  return __builtin_bit_cast(f16x2, __builtin_amdgcn_cvt_pkrtz(a, b));
}

// ----------------------------- convert kernel ------------------------------
// blocks [0,4096): x -> xb ; blocks [4096,8192): Wq..Wo -> wb

__global__ void cvt_all_kernel(const float* __restrict__ x,
                               const float* __restrict__ w0,
                               const float* __restrict__ w1,
                               const float* __restrict__ w2,
                               const float* __restrict__ w3,
                               _Float16* __restrict__ xb,
                               _Float16* __restrict__ wb) {
  const int bid = blockIdx.x;
  const float* src;
  _Float16* dst;
  int idx;
  if (bid < 4096) {
    src = x; dst = xb; idx = bid * 256 + threadIdx.x;
  } else {
    const int j = bid - 4096;
    const int y = j >> 10;
    src = (y == 0) ? w0 : (y == 1) ? w1 : (y == 2) ? w2 : w3;
    dst = wb + (size_t)y * (DM * DM);
    idx = (j & 1023) * 256 + threadIdx.x;
  }
  const float4 v = ((const float4*)src)[idx];
  f16x4 h;
  h[0] = (_Float16)v.x; h[1] = (_Float16)v.y;
  h[2] = (_Float16)v.z; h[3] = (_Float16)v.w;
  ((f16x4*)dst)[idx] = h;
}

// ------------------------- QKV GEMM (BK=64, 2 slabs) ------------------------
// z=0: Q (bias, *0.125*log2e, QF layout); z=1: K (KF); z=2: V (VF)

__global__ __launch_bounds__(256, 2) void gemm_qkv_kernel(
    const _Float16* __restrict__ xb, const _Float16* __restrict__ wb,
    const float* __restrict__ bq, const float* __restrict__ bk,
    const float* __restrict__ bv, _Float16* __restrict__ qkv)
{
  __shared__ _Float16 As[2][128 * 32];   // slab h: k in [k0+32h, k0+32h+32)
  __shared__ _Float16 Ws[2][128 * 32];
  const int z = blockIdx.z;
  const _Float16* W = wb + (size_t)z * (DM * DM);
  const float* bias = (z == 0) ? bq : ((z == 1) ? bk : bv);
  _Float16* out = qkv + (size_t)z * 4194304;

  const f32x4 z4 = {0.f, 0.f, 0.f, 0.f};
  f32x4 acc[4][4];
#pragma unroll
  for (int mi = 0; mi < 4; ++mi)
#pragma unroll
    for (int ni = 0; ni < 4; ++ni) acc[mi][ni] = z4;

  const int m0 = blockIdx.y * 128, n0 = blockIdx.x * 128;
  const int t = threadIdx.x;
  const int w = t >> 6, l = t & 63;
  const int quad = l >> 4, ln = l & 15;
  const int wm = (w >> 1) << 6, wn = (w & 1) << 6;
  const int srow = l >> 2, scol = (l & 3) << 3;

  for (int k0 = 0; k0 < DM; k0 += 64) {
#pragma unroll
    for (int h = 0; h < 2; ++h)
#pragma unroll
      for (int i = 0; i < 2; ++i) {
        const int ra = w * 32 + i * 16;
        gload_lds16(&xb[(size_t)(m0 + ra + srow) * DM + k0 + h * 32 + scol],
                    &As[h][ra * 32]);
        gload_lds16(&W[(size_t)(n0 + ra + srow) * DM + k0 + h * 32 + scol],
                    &Ws[h][ra * 32]);
      }
    __syncthreads();

#pragma unroll
    for (int h = 0; h < 2; ++h) {
      f16x8 af[4], bf[4];
#pragma unroll
      for (int mi = 0; mi < 4; ++mi)
        af[mi] = *(const f16x8*)&As[h][(wm + mi * 16 + ln) * 32 + quad * 8];
#pragma unroll
      for (int ni = 0; ni < 4; ++ni)
        bf[ni] = *(const f16x8*)&Ws[h][(wn + ni * 16 + ln) * 32 + quad * 8];
#pragma unroll
      for (int mi = 0; mi < 4; ++mi)
#pragma unroll
        for (int ni = 0; ni < 4; ++ni)
          acc[mi][ni] = __builtin_amdgcn_mfma_f32_16x16x32_f16(
              af[mi], bf[ni], acc[mi][ni], 0, 0, 0);
    }
    __syncthreads();
  }

  // fold 1/sqrt(Dh) * log2(e) into Q so attention uses exp2
  const float scale = (z == 0) ? 0.18033688f : 1.0f;

#pragma unroll
  for (int ni = 0; ni < 4; ++ni) {
    const int c = n0 + wn + ni * 16 + ln;
    const float bias_c = bias[c];
    const int h = c >> 6, d = c & 63;
#pragma unroll
    for (int mi = 0; mi < 4; ++mi) {
      const int mb = m0 + wm + mi * 16 + quad * 4;
#pragma unroll
      for (int r = 0; r < 4; ++r) {
        const int mg = mb + r;
        const int b = mg >> 11, s = mg & 2047;
        const int bh = b * NH + h;
        const float v = (acc[mi][ni][r] + bias_c) * scale;
        size_t idx;
        if (z == 2)
          idx = (size_t)bh * 131072 + (s >> 5) * 2048 + (d >> 4) * 512 +
                ((s >> 3) & 3) * 128 + (d & 15) * 8 + (s & 7);
        else
          idx = (size_t)bh * 131072 + (s >> 4) * 1024 + (d >> 5) * 512 +
                ((d >> 3) & 3) * 128 + (s & 15) * 8 + (d & 7);
        out[idx] = (_Float16)v;
      }
    }
  }
}

// ------------- output GEMM (BK=64 two-slab, 128x64 tile, direct) ------------

__global__ __launch_bounds__(256, 2) void gemm_out_kernel(
    const _Float16* __restrict__ ob, const _Float16* __restrict__ wo,
    const float* __restrict__ bo, float* __restrict__ out)
{
  __shared__ _Float16 As[2][128 * 32];
  __shared__ _Float16 Ws[2][64 * 32];
  const f32x4 z4 = {0.f, 0.f, 0.f, 0.f};
  f32x4 acc[2][4];
#pragma unroll
  for (int mi = 0; mi < 2; ++mi)
#pragma unroll
    for (int ni = 0; ni < 4; ++ni) acc[mi][ni] = z4;

  const int m0 = blockIdx.y * 128, n0 = blockIdx.x * 64;
  const int t = threadIdx.x;
  const int w = t >> 6, l = t & 63;
  const int quad = l >> 4, ln = l & 15;
  const int srow = l >> 2, scol = (l & 3) << 3;

  for (int k0 = 0; k0 < DM; k0 += 64) {
#pragma unroll
    for (int h = 0; h < 2; ++h) {
#pragma unroll
      for (int i = 0; i < 2; ++i) {
        const int ra = w * 32 + i * 16;
        gload_lds16(&ob[(size_t)(m0 + ra + srow) * DM + k0 + h * 32 + scol],
                    &As[h][ra * 32]);
      }
      gload_lds16(&wo[(size_t)(n0 + w * 16 + srow) * DM + k0 + h * 32 + scol],
                  &Ws[h][w * 16 * 32]);
    }
    __syncthreads();

#pragma unroll
    for (int h = 0; h < 2; ++h) {
      f16x8 af[2], bf[4];
#pragma unroll
      for (int mi = 0; mi < 2; ++mi)
        af[mi] = *(const f16x8*)&As[h][(w * 32 + mi * 16 + ln) * 32 + quad * 8];
#pragma unroll
      for (int ni = 0; ni < 4; ++ni)
        bf[ni] = *(const f16x8*)&Ws[h][(ni * 16 + ln) * 32 + quad * 8];
#pragma unroll
      for (int mi = 0; mi < 2; ++mi)
#pragma unroll
        for (int ni = 0; ni < 4; ++ni)
          acc[mi][ni] = __builtin_amdgcn_mfma_f32_16x16x32_f16(
              af[mi], bf[ni], acc[mi][ni], 0, 0, 0);
    }
    __syncthreads();
  }

#pragma unroll
  for (int ni = 0; ni < 4; ++ni) {
    const int c = n0 + ni * 16 + ln;
    const float bias_c = bo[c];
#pragma unroll
    for (int mi = 0; mi < 2; ++mi) {
      const int mb = m0 + w * 32 + mi * 16 + quad * 4;
#pragma unroll
      for (int r = 0; r < 4; ++r)
        out[(size_t)(mb + r) * DM + c] = acc[mi][ni][r] + bias_c;
    }
  }
}

// ---------------------------- flash attention ------------------------------
// R17: 1024 blocks x 4 waves; block = (bh = i&31, q-block b = 31-(i>>5),
// 64 q-rows, longest first). Wave w owns q rows [b*64 + w*16, +16).
// KV tiles (32 rows, 4KB K + 4KB V, tile-contiguous in KF/VF) staged once
// per block into double-buffered LDS via global_load_lds (wave w stages
// segment w of each); all 4 waves consume from LDS. Pipeline per tile:
// stage t+1 -> s_waitcnt vmcnt(2) -> s_barrier -> compute t -> s_barrier
// (counted vmcnt: prefetch stays in flight across barriers).
// Ps: stride 64 halfs, slot = (rg + 2*ln) & 15 (conflict-free, R15).
// Wave diag tile Dw = 2b + (w>>1); mask compares vs (w&1)*16 + ln.

template <bool DIAG>
__device__ __forceinline__ void tile_lds(
    const _Float16* __restrict__ Kls, const _Float16* __restrict__ Vls,
    const f16x8 (&qf)[2], f32x4 (&oacc)[4], float& l_i,
    _Float16* Ps, int quad, int ln, int l, int hq)
{
  const f32x4 z4 = {0.f, 0.f, 0.f, 0.f};
  f16x8 kv[4];

  // K phase (from LDS)
#pragma unroll
  for (int ii = 0; ii < 4; ++ii)
    kv[ii] = *(const f16x8*)&Kls[ii * 512 + l * 8];

  f32x4 sacc[2];
  sacc[0] = z4; sacc[1] = z4;
#pragma unroll
  for (int ks = 0; ks < 2; ++ks)
#pragma unroll
    for (int mi = 0; mi < 2; ++mi)
      sacc[mi] = __builtin_amdgcn_mfma_f32_16x16x32_f16(
          kv[mi * 2 + ks], qf[ks], sacc[mi], 0, 0, 0);

  // V phase (reuses kv registers, from LDS)
#pragma unroll
  for (int ii = 0; ii < 4; ++ii)
    kv[ii] = *(const f16x8*)&Vls[ii * 512 + l * 8];

  float rs = 0.f;
#pragma unroll
  for (int mi = 0; mi < 2; ++mi) {
    float p[4];
#pragma unroll
    for (int r = 0; r < 4; ++r) {
      p[r] = __builtin_amdgcn_exp2f(sacc[mi][r]);
      if (DIAG && (mi * 16 + quad * 4 + r > hq + ln)) p[r] = 0.f;
      rs += p[r];
    }
    const f16x2 lo = pkrtz(p[0], p[1]);
    const f16x2 hi = pkrtz(p[2], p[3]);
    const f16x4 pk = __builtin_shufflevector(lo, hi, 0, 1, 2, 3);
    // slot swizzle: stride 64 halfs (128 B) -> row drops out of bank index.
    const int slot = ((mi * 4 + quad) + 2 * ln) & 15;
    *(f16x4*)&Ps[ln * 64 + slot * 4] = pk;
  }
  l_i += rs;

  const int slot2 = ((quad * 2) + 2 * ln) & 15;  // even -> 16B aligned
  const f16x8 pb = *(const f16x8*)&Ps[ln * 64 + slot2 * 4];

#pragma unroll
  for (int di = 0; di < 4; ++di)
    oacc[di] = __builtin_amdgcn_mfma_f32_16x16x32_f16(
        kv[di], pb, oacc[di], 0, 0, 0);
}

__global__ __launch_bounds__(256, 6) void attn_kernel(
    const _Float16* __restrict__ QF, const _Float16* __restrict__ KF,
    const _Float16* __restrict__ VF, _Float16* __restrict__ Ob)
{
  __shared__ _Float16 KVs[2][2][2048];   // [buf][K=0/V=1][tile] : 16 KB
  __shared__ _Float16 Ps[4 * 16 * 64];   // 8 KB (2 KB/wave)

  const int i = blockIdx.x;
  const int bh = i & 31;                 // 4 heads per XCD, L2-resident KV
  const int b  = 31 - (i >> 5);          // q-block (64 rows); longest first
  const int T  = 2 * b + 2;              // kv tiles for this block

  const int tid = threadIdx.x;
  const int w = tid >> 6, l = tid & 63;
  const int quad = l >> 4, ln = l & 15;
  const int hq = (w & 1) << 4;           // q-row offset within diag tile
  const int Dw = 2 * b + (w >> 1);       // wave's diagonal tile index

  const _Float16* qb_ = QF + (size_t)bh * 131072;
  const _Float16* kb_ = KF + (size_t)bh * 131072;
  const _Float16* vb_ = VF + (size_t)bh * 131072;
  _Float16* psw = Ps + w * 1024;
  const int bidx = bh >> 4, hh = bh & 15;

  // Q fragments for rows [b*64 + w*16, +16): row-block rb = 4b + w
  f16x8 qf[2];
#pragma unroll
  for (int ks = 0; ks < 2; ++ks)
    qf[ks] = *(const f16x8*)
        (qb_ + (size_t)((4 * b + w) * 2 + ks) * 512 + l * 8);

  const f32x4 z4 = {0.f, 0.f, 0.f, 0.f};
  f32x4 oacc[4];
#pragma unroll
  for (int di = 0; di < 4; ++di) oacc[di] = z4;
  float l_i = 0.f;

  // prologue: stage tile 0 into buf 0 (wave w stages segment w of K and V)
  gload_lds16(&kb_[(size_t)w * 512 + l * 8], &KVs[0][0][w * 512]);
  gload_lds16(&vb_[(size_t)w * 512 + l * 8], &KVs[0][1][w * 512]);

  for (int t = 0; t < T; ++t) {
    const int cur = t & 1;
    if (t + 1 < T) {
      gload_lds16(&kb_[(size_t)(t + 1) * 2048 + w * 512 + l * 8],
                  &KVs[cur ^ 1][0][w * 512]);
      gload_lds16(&vb_[(size_t)(t + 1) * 2048 + w * 512 + l * 8],
                  &KVs[cur ^ 1][1][w * 512]);
      asm volatile("s_waitcnt vmcnt(2)" ::: "memory");  // tile t landed
    } else {
      asm volatile("s_waitcnt vmcnt(0)" ::: "memory");
    }
    __builtin_amdgcn_s_barrier();            // all waves' tile-t stage done
    __builtin_amdgcn_sched_barrier(0);
    if (t < Dw)
      tile_lds<false>(&KVs[cur][0][0], &KVs[cur][1][0], qf, oacc, l_i,
                      psw, quad, ln, l, hq);
    else if (t == Dw)
      tile_lds<true>(&KVs[cur][0][0], &KVs[cur][1][0], qf, oacc, l_i,
                     psw, quad, ln, l, hq);
    __builtin_amdgcn_sched_barrier(0);
    __builtin_amdgcn_s_barrier();            // readers done before overwrite
  }

  // row-sum across the 4 quads (lanes ln, ln+16, ln+32, ln+48)
  l_i += __shfl_xor(l_i, 16);
  l_i += __shfl_xor(l_i, 32);
  const float inv = 1.0f / l_i;

  const int q = b * 64 + w * 16 + ln;
  _Float16* orow = Ob + (size_t)(bidx * S_ + q) * DM + hh * DH + quad * 4;
#pragma unroll
  for (int di = 0; di < 4; ++di) {
    f16x4 o4;
#pragma unroll
    for (int r = 0; r < 4; ++r)
      o4[r] = (_Float16)(oacc[di][r] * inv);
    *(f16x4*)(orow + di * 16) = o4;
  }
}

// ------------------------------- launcher ----------------------------------

extern "C" void kernel_launch(void* const* d_in, const int* in_sizes, int n_in,
                              void* d_out, int out_size, void* d_ws, size_t ws_size,
                              hipStream_t stream) {
  (void)in_sizes; (void)n_in; (void)out_size; (void)ws_size;
  const float* x  = (const float*)d_in[0];
  const float* Wq = (const float*)d_in[1];
  const float* bq = (const float*)d_in[2];
  const float* Wk = (const float*)d_in[3];
  const float* bk = (const float*)d_in[4];
  const float* Wv = (const float*)d_in[5];
  const float* bv = (const float*)d_in[6];
  const float* Wo = (const float*)d_in[7];
  const float* bo = (const float*)d_in[8];

  char* ws = (char*)d_ws;
  _Float16* xb  = (_Float16*)(ws);                      // 8 MB
  _Float16* wb  = (_Float16*)(ws + (8u << 20));         // 4 x 2 MB
  _Float16* qkv = (_Float16*)(ws + (16u << 20));        // QF,KF,VF 8 MB each
  _Float16* ob  = (_Float16*)(ws + (40u << 20));        // 8 MB

  cvt_all_kernel<<<dim3(8192), dim3(256), 0, stream>>>(x, Wq, Wk, Wv, Wo, xb, wb);
  gemm_qkv_kernel<<<dim3(8, 32, 3), dim3(256), 0, stream>>>(xb, wb, bq, bk, bv, qkv);
  attn_kernel<<<dim3(1024), dim3(256), 0, stream>>>(
      qkv, qkv + 4194304, qkv + 2 * 4194304, ob);
  gemm_out_kernel<<<dim3(16, 32), dim3(256), 0, stream>>>(
      ob, wb + (size_t)3 * DM * DM, bo, (float*)d_out);
}

// Round 6
// 183.133 us; speedup vs baseline: 1.0175x; 1.0175x over previous
//
#include <hip/hip_runtime.h>

// ---------------------------------------------------------------------------
// StandardMultiHeadAttention: B=2, S=2048, D=1024, H=16, Dh=64, causal.
// fp32->f16 convert -> QKV GEMM (BK=64, frag-major epilogue) -> flash
// attention (LDS-staged KV, 2-deep unit pipeline) -> output GEMM.
//
// Workspace (48 MB):
//   [0,8M)    xb : x f16 [4096,1024]
//   [8M,16M)  wb : Wq,Wk,Wv,Wo f16 (row=out, K-major)
//   [16M,24M) QF : Q frag-major (pre-scaled by 0.125*log2e)
//   [24M,32M) KF : K frag-major (tile-contiguous, 2048 halfs / 32-row tile)
//   [32M,40M) VF : V^T frag-major (same tiling)
//   [40M,48M) ob : attention output [B,S,1024] f16
//
// R18 post-mortem of R17: VMEM cut 4x as designed, time STILL 43.5us (6th
// structure pinned there). Time independent of occupancy (22-49%) AND no
// pipe saturated (Mfma 14, VALU 22, HBM 6, LDS<50%) -> convoy: block's
// waves run identical streams in lockstep; pipes see same-phase bursts and
// never overlap across phases; per-pipe busy == serial-chain share. Fix
// that works under convoy: within-wave ILP across INDEPENDENT chains.
// Static-base softmax (no running max) -> KV tiles order-independent ->
// process 2 tiles/iter as two independent QK->exp2->Ps->PV chains (separate
// sacc, separate Ps A/B buffers, no barrier between) -> scheduler fills one
// chain's stalls with the other's work. Staging: 16KB pairs, dbuf, counted
// vmcnt(4) (prefetch in flight across barriers). Tail pair: (diag,skip) for
// wave-group 0, (full,diag) for group 1. LDS 48KB -> 3 blocks/CU (theory
// says occupancy-insensitive; this is also the test of that claim).
// ---------------------------------------------------------------------------

typedef _Float16 f16x8 __attribute__((ext_vector_type(8)));
typedef _Float16 f16x4 __attribute__((ext_vector_type(4)));
typedef _Float16 f16x2 __attribute__((ext_vector_type(2)));
typedef float f32x4 __attribute__((ext_vector_type(4)));

#define S_  2048
#define DM  1024
#define NH  16
#define DH  64

__device__ __forceinline__ void gload_lds16(const void* g, void* s) {
  __builtin_amdgcn_global_load_lds(
      (const __attribute__((address_space(1))) void*)g,
      (__attribute__((address_space(3))) void*)s, 16, 0, 0);
}

__device__ __forceinline__ f16x2 pkrtz(float a, float b) {
  return __builtin_bit_cast(f16x2, __builtin_amdgcn_cvt_pkrtz(a, b));
}

// ----------------------------- convert kernel ------------------------------
// blocks [0,4096): x -> xb ; blocks [4096,8192): Wq..Wo -> wb

__global__ void cvt_all_kernel(const float* __restrict__ x,
                               const float* __restrict__ w0,
                               const float* __restrict__ w1,
                               const float* __restrict__ w2,
                               const float* __restrict__ w3,
                               _Float16* __restrict__ xb,
                               _Float16* __restrict__ wb) {
  const int bid = blockIdx.x;
  const float* src;
  _Float16* dst;
  int idx;
  if (bid < 4096) {
    src = x; dst = xb; idx = bid * 256 + threadIdx.x;
  } else {
    const int j = bid - 4096;
    const int y = j >> 10;
    src = (y == 0) ? w0 : (y == 1) ? w1 : (y == 2) ? w2 : w3;
    dst = wb + (size_t)y * (DM * DM);
    idx = (j & 1023) * 256 + threadIdx.x;
  }
  const float4 v = ((const float4*)src)[idx];
  f16x4 h;
  h[0] = (_Float16)v.x; h[1] = (_Float16)v.y;
  h[2] = (_Float16)v.z; h[3] = (_Float16)v.w;
  ((f16x4*)dst)[idx] = h;
}

// ------------------------- QKV GEMM (BK=64, 2 slabs) ------------------------
// z=0: Q (bias, *0.125*log2e, QF layout); z=1: K (KF); z=2: V (VF)

__global__ __launch_bounds__(256, 2) void gemm_qkv_kernel(
    const _Float16* __restrict__ xb, const _Float16* __restrict__ wb,
    const float* __restrict__ bq, const float* __restrict__ bk,
    const float* __restrict__ bv, _Float16* __restrict__ qkv)
{
  __shared__ _Float16 As[2][128 * 32];   // slab h: k in [k0+32h, k0+32h+32)
  __shared__ _Float16 Ws[2][128 * 32];
  const int z = blockIdx.z;
  const _Float16* W = wb + (size_t)z * (DM * DM);
  const float* bias = (z == 0) ? bq : ((z == 1) ? bk : bv);
  _Float16* out = qkv + (size_t)z * 4194304;

  const f32x4 z4 = {0.f, 0.f, 0.f, 0.f};
  f32x4 acc[4][4];
#pragma unroll
  for (int mi = 0; mi < 4; ++mi)
#pragma unroll
    for (int ni = 0; ni < 4; ++ni) acc[mi][ni] = z4;

  const int m0 = blockIdx.y * 128, n0 = blockIdx.x * 128;
  const int t = threadIdx.x;
  const int w = t >> 6, l = t & 63;
  const int quad = l >> 4, ln = l & 15;
  const int wm = (w >> 1) << 6, wn = (w & 1) << 6;
  const int srow = l >> 2, scol = (l & 3) << 3;

  for (int k0 = 0; k0 < DM; k0 += 64) {
#pragma unroll
    for (int h = 0; h < 2; ++h)
#pragma unroll
      for (int i = 0; i < 2; ++i) {
        const int ra = w * 32 + i * 16;
        gload_lds16(&xb[(size_t)(m0 + ra + srow) * DM + k0 + h * 32 + scol],
                    &As[h][ra * 32]);
        gload_lds16(&W[(size_t)(n0 + ra + srow) * DM + k0 + h * 32 + scol],
                    &Ws[h][ra * 32]);
      }
    __syncthreads();

#pragma unroll
    for (int h = 0; h < 2; ++h) {
      f16x8 af[4], bf[4];
#pragma unroll
      for (int mi = 0; mi < 4; ++mi)
        af[mi] = *(const f16x8*)&As[h][(wm + mi * 16 + ln) * 32 + quad * 8];
#pragma unroll
      for (int ni = 0; ni < 4; ++ni)
        bf[ni] = *(const f16x8*)&Ws[h][(wn + ni * 16 + ln) * 32 + quad * 8];
#pragma unroll
      for (int mi = 0; mi < 4; ++mi)
#pragma unroll
        for (int ni = 0; ni < 4; ++ni)
          acc[mi][ni] = __builtin_amdgcn_mfma_f32_16x16x32_f16(
              af[mi], bf[ni], acc[mi][ni], 0, 0, 0);
    }
    __syncthreads();
  }

  // fold 1/sqrt(Dh) * log2(e) into Q so attention uses exp2
  const float scale = (z == 0) ? 0.18033688f : 1.0f;

#pragma unroll
  for (int ni = 0; ni < 4; ++ni) {
    const int c = n0 + wn + ni * 16 + ln;
    const float bias_c = bias[c];
    const int h = c >> 6, d = c & 63;
#pragma unroll
    for (int mi = 0; mi < 4; ++mi) {
      const int mb = m0 + wm + mi * 16 + quad * 4;
#pragma unroll
      for (int r = 0; r < 4; ++r) {
        const int mg = mb + r;
        const int b = mg >> 11, s = mg & 2047;
        const int bh = b * NH + h;
        const float v = (acc[mi][ni][r] + bias_c) * scale;
        size_t idx;
        if (z == 2)
          idx = (size_t)bh * 131072 + (s >> 5) * 2048 + (d >> 4) * 512 +
                ((s >> 3) & 3) * 128 + (d & 15) * 8 + (s & 7);
        else
          idx = (size_t)bh * 131072 + (s >> 4) * 1024 + (d >> 5) * 512 +
                ((d >> 3) & 3) * 128 + (s & 15) * 8 + (d & 7);
        out[idx] = (_Float16)v;
      }
    }
  }
}

// ------------- output GEMM (BK=64 two-slab, 128x64 tile, direct) ------------

__global__ __launch_bounds__(256, 2) void gemm_out_kernel(
    const _Float16* __restrict__ ob, const _Float16* __restrict__ wo,
    const float* __restrict__ bo, float* __restrict__ out)
{
  __shared__ _Float16 As[2][128 * 32];
  __shared__ _Float16 Ws[2][64 * 32];
  const f32x4 z4 = {0.f, 0.f, 0.f, 0.f};
  f32x4 acc[2][4];
#pragma unroll
  for (int mi = 0; mi < 2; ++mi)
#pragma unroll
    for (int ni = 0; ni < 4; ++ni) acc[mi][ni] = z4;

  const int m0 = blockIdx.y * 128, n0 = blockIdx.x * 64;
  const int t = threadIdx.x;
  const int w = t >> 6, l = t & 63;
  const int quad = l >> 4, ln = l & 15;
  const int srow = l >> 2, scol = (l & 3) << 3;

  for (int k0 = 0; k0 < DM; k0 += 64) {
#pragma unroll
    for (int h = 0; h < 2; ++h) {
#pragma unroll
      for (int i = 0; i < 2; ++i) {
        const int ra = w * 32 + i * 16;
        gload_lds16(&ob[(size_t)(m0 + ra + srow) * DM + k0 + h * 32 + scol],
                    &As[h][ra * 32]);
      }
      gload_lds16(&wo[(size_t)(n0 + w * 16 + srow) * DM + k0 + h * 32 + scol],
                  &Ws[h][w * 16 * 32]);
    }
    __syncthreads();

#pragma unroll
    for (int h = 0; h < 2; ++h) {
      f16x8 af[2], bf[4];
#pragma unroll
      for (int mi = 0; mi < 2; ++mi)
        af[mi] = *(const f16x8*)&As[h][(w * 32 + mi * 16 + ln) * 32 + quad * 8];
#pragma unroll
      for (int ni = 0; ni < 4; ++ni)
        bf[ni] = *(const f16x8*)&Ws[h][(ni * 16 + ln) * 32 + quad * 8];
#pragma unroll
      for (int mi = 0; mi < 2; ++mi)
#pragma unroll
        for (int ni = 0; ni < 4; ++ni)
          acc[mi][ni] = __builtin_amdgcn_mfma_f32_16x16x32_f16(
              af[mi], bf[ni], acc[mi][ni], 0, 0, 0);
    }
    __syncthreads();
  }

#pragma unroll
  for (int ni = 0; ni < 4; ++ni) {
    const int c = n0 + ni * 16 + ln;
    const float bias_c = bo[c];
#pragma unroll
    for (int mi = 0; mi < 2; ++mi) {
      const int mb = m0 + w * 32 + mi * 16 + quad * 4;
#pragma unroll
      for (int r = 0; r < 4; ++r)
        out[(size_t)(mb + r) * DM + c] = acc[mi][ni][r] + bias_c;
    }
  }
}

// ---------------------------- flash attention ------------------------------
// R18: 1024 blocks x 4 waves; block = (bh = i&31, q-block b = 31-(i>>5),
// 64 q-rows, longest first). Wave w owns q rows [b*64 + w*16, +16).
// KV staged in PAIRS of 32-row tiles (16KB/pair) into double-buffered LDS;
// per iteration the wave runs TWO independent chains (tiles 2pr, 2pr+1:
// separate sacc, separate Ps A/B) with no barrier between -> scheduler
// interleaves them, breaking the convoy/serial-chain. Counted vmcnt(4):
// next pair's 4 stage-loads stay in flight across barriers. Tail pair:
// wave-group g=0 (Dw=2b): (diag, skip); g=1 (Dw=2b+1): (full, diag).

template <int MODE>   // 0 = full tile, 1 = diagonal (causal mask)
__device__ __forceinline__ void tile_lds(
    const _Float16* __restrict__ Kls, const _Float16* __restrict__ Vls,
    const f16x8 (&qf)[2], f32x4 (&oacc)[4], float& l_i,
    _Float16* Ps, int quad, int ln, int l, int hq)
{
  const f32x4 z4 = {0.f, 0.f, 0.f, 0.f};
  f16x8 kv[4];

  // K phase (from LDS)
#pragma unroll
  for (int ii = 0; ii < 4; ++ii)
    kv[ii] = *(const f16x8*)&Kls[ii * 512 + l * 8];

  f32x4 sacc[2];
  sacc[0] = z4; sacc[1] = z4;
#pragma unroll
  for (int ks = 0; ks < 2; ++ks)
#pragma unroll
    for (int mi = 0; mi < 2; ++mi)
      sacc[mi] = __builtin_amdgcn_mfma_f32_16x16x32_f16(
          kv[mi * 2 + ks], qf[ks], sacc[mi], 0, 0, 0);

  // V phase (reuses kv registers, from LDS)
#pragma unroll
  for (int ii = 0; ii < 4; ++ii)
    kv[ii] = *(const f16x8*)&Vls[ii * 512 + l * 8];

  float rs = 0.f;
#pragma unroll
  for (int mi = 0; mi < 2; ++mi) {
    float p[4];
#pragma unroll
    for (int r = 0; r < 4; ++r) {
      p[r] = __builtin_amdgcn_exp2f(sacc[mi][r]);
      if (MODE == 1 && (mi * 16 + quad * 4 + r > hq + ln)) p[r] = 0.f;
      rs += p[r];
    }
    const f16x2 lo = pkrtz(p[0], p[1]);
    const f16x2 hi = pkrtz(p[2], p[3]);
    const f16x4 pk = __builtin_shufflevector(lo, hi, 0, 1, 2, 3);
    // slot swizzle: stride 64 halfs (128 B) -> row drops out of bank index.
    const int slot = ((mi * 4 + quad) + 2 * ln) & 15;
    *(f16x4*)&Ps[ln * 64 + slot * 4] = pk;
  }
  l_i += rs;

  const int slot2 = ((quad * 2) + 2 * ln) & 15;  // even -> 16B aligned
  const f16x8 pb = *(const f16x8*)&Ps[ln * 64 + slot2 * 4];

#pragma unroll
  for (int di = 0; di < 4; ++di)
    oacc[di] = __builtin_amdgcn_mfma_f32_16x16x32_f16(
        kv[di], pb, oacc[di], 0, 0, 0);
}

__global__ __launch_bounds__(256, 3) void attn_kernel(
    const _Float16* __restrict__ QF, const _Float16* __restrict__ KF,
    const _Float16* __restrict__ VF, _Float16* __restrict__ Ob)
{
  __shared__ _Float16 KVs[2][2][4096];   // [buf][K/V][pair: tile0|tile1] 32KB
  __shared__ _Float16 Ps[4][2][1024];    // [wave][chain A/B] 16KB

  const int i = blockIdx.x;
  const int bh = i & 31;                 // 4 heads per XCD, L2-resident KV
  const int b  = 31 - (i >> 5);          // q-block (64 rows); longest first

  const int tid = threadIdx.x;
  const int w = tid >> 6, l = tid & 63;
  const int quad = l >> 4, ln = l & 15;
  const int hq = (w & 1) << 4;           // q-row offset within diag tile
  const int g  = w >> 1;                 // 0: Dw=2b, 1: Dw=2b+1

  const _Float16* qb_ = QF + (size_t)bh * 131072;
  const _Float16* kb_ = KF + (size_t)bh * 131072;
  const _Float16* vb_ = VF + (size_t)bh * 131072;
  _Float16* psA = &Ps[w][0][0];
  _Float16* psB = &Ps[w][1][0];
  const int bidx = bh >> 4, hh = bh & 15;

  // Q fragments for rows [b*64 + w*16, +16): row-block rb = 4b + w
  f16x8 qf[2];
#pragma unroll
  for (int ks = 0; ks < 2; ++ks)
    qf[ks] = *(const f16x8*)
        (qb_ + (size_t)((4 * b + w) * 2 + ks) * 512 + l * 8);

  const f32x4 z4 = {0.f, 0.f, 0.f, 0.f};
  f32x4 oacc[4];
#pragma unroll
  for (int di = 0; di < 4; ++di) oacc[di] = z4;
  float l_i = 0.f;

  // prologue: stage pair 0 (tiles 0,1) into buf 0; wave w stages segment w
  gload_lds16(&kb_[(size_t)w * 512 + l * 8],        &KVs[0][0][w * 512]);
  gload_lds16(&kb_[(size_t)(2048 + w * 512) + l * 8], &KVs[0][0][2048 + w * 512]);
  gload_lds16(&vb_[(size_t)w * 512 + l * 8],        &KVs[0][1][w * 512]);
  gload_lds16(&vb_[(size_t)(2048 + w * 512) + l * 8], &KVs[0][1][2048 + w * 512]);

  for (int pr = 0; pr <= b; ++pr) {
    const int cur = pr & 1;
    if (pr < b) {
      const size_t off = (size_t)(pr + 1) * 4096;
      gload_lds16(&kb_[off + w * 512 + l * 8],        &KVs[cur ^ 1][0][w * 512]);
      gload_lds16(&kb_[off + 2048 + w * 512 + l * 8], &KVs[cur ^ 1][0][2048 + w * 512]);
      gload_lds16(&vb_[off + w * 512 + l * 8],        &KVs[cur ^ 1][1][w * 512]);
      gload_lds16(&vb_[off + 2048 + w * 512 + l * 8], &KVs[cur ^ 1][1][2048 + w * 512]);
      asm volatile("s_waitcnt vmcnt(4)" ::: "memory");  // this pair landed
    } else {
      asm volatile("s_waitcnt vmcnt(0)" ::: "memory");
    }
    __builtin_amdgcn_s_barrier();          // all waves' stage of this pair done
    __builtin_amdgcn_sched_barrier(0);
    const _Float16* K0 = &KVs[cur][0][0];
    const _Float16* V0 = &KVs[cur][1][0];
    if (pr < b) {
      // two independent full chains; no barrier between -> interleaved
      tile_lds<0>(K0,        V0,        qf, oacc, l_i, psA, quad, ln, l, hq);
      tile_lds<0>(K0 + 2048, V0 + 2048, qf, oacc, l_i, psB, quad, ln, l, hq);
    } else {
      if (g) {
        tile_lds<0>(K0,        V0,        qf, oacc, l_i, psA, quad, ln, l, hq);
        tile_lds<1>(K0 + 2048, V0 + 2048, qf, oacc, l_i, psB, quad, ln, l, hq);
      } else {
        tile_lds<1>(K0,        V0,        qf, oacc, l_i, psA, quad, ln, l, hq);
      }
    }
    __builtin_amdgcn_sched_barrier(0);
    __builtin_amdgcn_s_barrier();          // readers done before overwrite
  }

  // row-sum across the 4 quads (lanes ln, ln+16, ln+32, ln+48)
  l_i += __shfl_xor(l_i, 16);
  l_i += __shfl_xor(l_i, 32);
  const float inv = 1.0f / l_i;

  const int q = b * 64 + w * 16 + ln;
  _Float16* orow = Ob + (size_t)(bidx * S_ + q) * DM + hh * DH + quad * 4;
#pragma unroll
  for (int di = 0; di < 4; ++di) {
    f16x4 o4;
#pragma unroll
    for (int r = 0; r < 4; ++r)
      o4[r] = (_Float16)(oacc[di][r] * inv);
    *(f16x4*)(orow + di * 16) = o4;
  }
}

// ------------------------------- launcher ----------------------------------

extern "C" void kernel_launch(void* const* d_in, const int* in_sizes, int n_in,
                              void* d_out, int out_size, void* d_ws, size_t ws_size,
                              hipStream_t stream) {
  (void)in_sizes; (void)n_in; (void)out_size; (void)ws_size;
  const float* x  = (const float*)d_in[0];
  const float* Wq = (const float*)d_in[1];
  const float* bq = (const float*)d_in[2];
  const float* Wk = (const float*)d_in[3];
  const float* bk = (const float*)d_in[4];
  const float* Wv = (const float*)d_in[5];
  const float* bv = (const float*)d_in[6];
  const float* Wo = (const float*)d_in[7];
  const float* bo = (const float*)d_in[8];

  char* ws = (char*)d_ws;
  _Float16* xb  = (_Float16*)(ws);                      // 8 MB
  _Float16* wb  = (_Float16*)(ws + (8u << 20));         // 4 x 2 MB
  _Float16* qkv = (_Float16*)(ws + (16u << 20));        // QF,KF,VF 8 MB each
  _Float16* ob  = (_Float16*)(ws + (40u << 20));        // 8 MB

  cvt_all_kernel<<<dim3(8192), dim3(256), 0, stream>>>(x, Wq, Wk, Wv, Wo, xb, wb);
  gemm_qkv_kernel<<<dim3(8, 32, 3), dim3(256), 0, stream>>>(xb, wb, bq, bk, bv, qkv);
  attn_kernel<<<dim3(1024), dim3(256), 0, stream>>>(
      qkv, qkv + 4194304, qkv + 2 * 4194304, ob);
  gemm_out_kernel<<<dim3(16, 32), dim3(256), 0, stream>>>(
      ob, wb + (size_t)3 * DM * DM, bo, (float*)d_out);
}

// Round 7
// 181.799 us; speedup vs baseline: 1.0250x; 1.0073x over previous
//
#include <hip/hip_runtime.h>

// ---------------------------------------------------------------------------
// StandardMultiHeadAttention: B=2, S=2048, D=1024, H=16, Dh=64, causal.
// fp32->f16 convert -> QKV GEMM (BK=64, frag-major epilogue) -> flash
// attention (64 q-rows/wave, K/V global->reg, intensity 4x) -> output GEMM.
//
// Workspace (48 MB):
//   [0,8M)    xb : x f16 [4096,1024]
//   [8M,16M)  wb : Wq,Wk,Wv,Wo f16 (row=out, K-major)
//   [16M,24M) QF : Q frag-major (pre-scaled by 0.125*log2e)
//   [24M,32M) KF : K frag-major (tile-contiguous, 2048 halfs / 32-row tile)
//   [32M,40M) VF : V^T frag-major (same tiling)
//   [40M,48M) ob : attention output [B,S,1024] f16
//
// R19 post-mortem of R13-R18: SEVEN attn structures pinned at ~43us across
// occupancy 22-49%, VMEM 4x, barriers 0-4/tile, conflicts 6x, ILP 1-2.
// Common invariant: 8KB of K/V moved into regs per 8 MFMA (16 q-rows) =
// intensity 1 MFMA/KB. Whichever pipe carries it (L1-return R13/R16,
// LDS-port R17/R18) sits at ~10 MB/CU ~ 40us at ~100 B/cyc/CU data return.
// Occupancy/ILP can't help a per-CU byte budget; counters never showed it
// (L1-return/LDS-port busy not in set).
// R19: 64 q-rows per WAVE (qf[4][2], oacc[4][4]): 8KB K/V tile feeds 32
// MFMA (4x intensity). K/V global->reg direct (no LDS staging, no convoy
// barriers): K/V traffic 270 MB total (~1 MB/CU). LDS only for Ps (270 MB)
// + one end-of-block merge. Block = 2 waves (128 thr) = (bh, 64-row qblock);
// kv tiles split by parity (qb+1 each, balanced); 1 syncthreads/block.
// 1024 blocks longest-first; bh=i&31 keeps heads XCD-local. ~165 VGPR ->
// 3 waves/SIMD; LDS 21 KB -> 6 blocks/CU. Causality per 16-row sub-tile:
// t<2qb full; t=2qb diag(qs0,1)/full(qs2,3); t=2qb+1 skip/diag(qs2,3).
// ---------------------------------------------------------------------------

typedef _Float16 f16x8 __attribute__((ext_vector_type(8)));
typedef _Float16 f16x4 __attribute__((ext_vector_type(4)));
typedef _Float16 f16x2 __attribute__((ext_vector_type(2)));
typedef float f32x4 __attribute__((ext_vector_type(4)));

#define S_  2048
#define DM  1024
#define NH  16
#define DH  64

__device__ __forceinline__ void gload_lds16(const void* g, void* s) {
  __builtin_amdgcn_global_load_lds(
      (const __attribute__((address_space(1))) void*)g,
      (__attribute__((address_space(3))) void*)s, 16, 0, 0);
}

__device__ __forceinline__ f16x2 pkrtz(float a, float b) {
  return __builtin_bit_cast(f16x2, __builtin_amdgcn_cvt_pkrtz(a, b));
}

// ----------------------------- convert kernel ------------------------------
// blocks [0,4096): x -> xb ; blocks [4096,8192): Wq..Wo -> wb

__global__ void cvt_all_kernel(const float* __restrict__ x,
                               const float* __restrict__ w0,
                               const float* __restrict__ w1,
                               const float* __restrict__ w2,
                               const float* __restrict__ w3,
                               _Float16* __restrict__ xb,
                               _Float16* __restrict__ wb) {
  const int bid = blockIdx.x;
  const float* src;
  _Float16* dst;
  int idx;
  if (bid < 4096) {
    src = x; dst = xb; idx = bid * 256 + threadIdx.x;
  } else {
    const int j = bid - 4096;
    const int y = j >> 10;
    src = (y == 0) ? w0 : (y == 1) ? w1 : (y == 2) ? w2 : w3;
    dst = wb + (size_t)y * (DM * DM);
    idx = (j & 1023) * 256 + threadIdx.x;
  }
  const float4 v = ((const float4*)src)[idx];
  f16x4 h;
  h[0] = (_Float16)v.x; h[1] = (_Float16)v.y;
  h[2] = (_Float16)v.z; h[3] = (_Float16)v.w;
  ((f16x4*)dst)[idx] = h;
}

// ------------------------- QKV GEMM (BK=64, 2 slabs) ------------------------
// z=0: Q (bias, *0.125*log2e, QF layout); z=1: K (KF); z=2: V (VF)

__global__ __launch_bounds__(256, 2) void gemm_qkv_kernel(
    const _Float16* __restrict__ xb, const _Float16* __restrict__ wb,
    const float* __restrict__ bq, const float* __restrict__ bk,
    const float* __restrict__ bv, _Float16* __restrict__ qkv)
{
  __shared__ _Float16 As[2][128 * 32];   // slab h: k in [k0+32h, k0+32h+32)
  __shared__ _Float16 Ws[2][128 * 32];
  const int z = blockIdx.z;
  const _Float16* W = wb + (size_t)z * (DM * DM);
  const float* bias = (z == 0) ? bq : ((z == 1) ? bk : bv);
  _Float16* out = qkv + (size_t)z * 4194304;

  const f32x4 z4 = {0.f, 0.f, 0.f, 0.f};
  f32x4 acc[4][4];
#pragma unroll
  for (int mi = 0; mi < 4; ++mi)
#pragma unroll
    for (int ni = 0; ni < 4; ++ni) acc[mi][ni] = z4;

  const int m0 = blockIdx.y * 128, n0 = blockIdx.x * 128;
  const int t = threadIdx.x;
  const int w = t >> 6, l = t & 63;
  const int quad = l >> 4, ln = l & 15;
  const int wm = (w >> 1) << 6, wn = (w & 1) << 6;
  const int srow = l >> 2, scol = (l & 3) << 3;

  for (int k0 = 0; k0 < DM; k0 += 64) {
#pragma unroll
    for (int h = 0; h < 2; ++h)
#pragma unroll
      for (int i = 0; i < 2; ++i) {
        const int ra = w * 32 + i * 16;
        gload_lds16(&xb[(size_t)(m0 + ra + srow) * DM + k0 + h * 32 + scol],
                    &As[h][ra * 32]);
        gload_lds16(&W[(size_t)(n0 + ra + srow) * DM + k0 + h * 32 + scol],
                    &Ws[h][ra * 32]);
      }
    __syncthreads();

#pragma unroll
    for (int h = 0; h < 2; ++h) {
      f16x8 af[4], bf[4];
#pragma unroll
      for (int mi = 0; mi < 4; ++mi)
        af[mi] = *(const f16x8*)&As[h][(wm + mi * 16 + ln) * 32 + quad * 8];
#pragma unroll
      for (int ni = 0; ni < 4; ++ni)
        bf[ni] = *(const f16x8*)&Ws[h][(wn + ni * 16 + ln) * 32 + quad * 8];
#pragma unroll
      for (int mi = 0; mi < 4; ++mi)
#pragma unroll
        for (int ni = 0; ni < 4; ++ni)
          acc[mi][ni] = __builtin_amdgcn_mfma_f32_16x16x32_f16(
              af[mi], bf[ni], acc[mi][ni], 0, 0, 0);
    }
    __syncthreads();
  }

  // fold 1/sqrt(Dh) * log2(e) into Q so attention uses exp2
  const float scale = (z == 0) ? 0.18033688f : 1.0f;

#pragma unroll
  for (int ni = 0; ni < 4; ++ni) {
    const int c = n0 + wn + ni * 16 + ln;
    const float bias_c = bias[c];
    const int h = c >> 6, d = c & 63;
#pragma unroll
    for (int mi = 0; mi < 4; ++mi) {
      const int mb = m0 + wm + mi * 16 + quad * 4;
#pragma unroll
      for (int r = 0; r < 4; ++r) {
        const int mg = mb + r;
        const int b = mg >> 11, s = mg & 2047;
        const int bh = b * NH + h;
        const float v = (acc[mi][ni][r] + bias_c) * scale;
        size_t idx;
        if (z == 2)
          idx = (size_t)bh * 131072 + (s >> 5) * 2048 + (d >> 4) * 512 +
                ((s >> 3) & 3) * 128 + (d & 15) * 8 + (s & 7);
        else
          idx = (size_t)bh * 131072 + (s >> 4) * 1024 + (d >> 5) * 512 +
                ((d >> 3) & 3) * 128 + (s & 15) * 8 + (d & 7);
        out[idx] = (_Float16)v;
      }
    }
  }
}

// ------------- output GEMM (BK=64 two-slab, 128x64 tile, direct) ------------

__global__ __launch_bounds__(256, 2) void gemm_out_kernel(
    const _Float16* __restrict__ ob, const _Float16* __restrict__ wo,
    const float* __restrict__ bo, float* __restrict__ out)
{
  __shared__ _Float16 As[2][128 * 32];
  __shared__ _Float16 Ws[2][64 * 32];
  const f32x4 z4 = {0.f, 0.f, 0.f, 0.f};
  f32x4 acc[2][4];
#pragma unroll
  for (int mi = 0; mi < 2; ++mi)
#pragma unroll
    for (int ni = 0; ni < 4; ++ni) acc[mi][ni] = z4;

  const int m0 = blockIdx.y * 128, n0 = blockIdx.x * 64;
  const int t = threadIdx.x;
  const int w = t >> 6, l = t & 63;
  const int quad = l >> 4, ln = l & 15;
  const int srow = l >> 2, scol = (l & 3) << 3;

  for (int k0 = 0; k0 < DM; k0 += 64) {
#pragma unroll
    for (int h = 0; h < 2; ++h) {
#pragma unroll
      for (int i = 0; i < 2; ++i) {
        const int ra = w * 32 + i * 16;
        gload_lds16(&ob[(size_t)(m0 + ra + srow) * DM + k0 + h * 32 + scol],
                    &As[h][ra * 32]);
      }
      gload_lds16(&wo[(size_t)(n0 + w * 16 + srow) * DM + k0 + h * 32 + scol],
                  &Ws[h][w * 16 * 32]);
    }
    __syncthreads();

#pragma unroll
    for (int h = 0; h < 2; ++h) {
      f16x8 af[2], bf[4];
#pragma unroll
      for (int mi = 0; mi < 2; ++mi)
        af[mi] = *(const f16x8*)&As[h][(w * 32 + mi * 16 + ln) * 32 + quad * 8];
#pragma unroll
      for (int ni = 0; ni < 4; ++ni)
        bf[ni] = *(const f16x8*)&Ws[h][(ni * 16 + ln) * 32 + quad * 8];
#pragma unroll
      for (int mi = 0; mi < 2; ++mi)
#pragma unroll
        for (int ni = 0; ni < 4; ++ni)
          acc[mi][ni] = __builtin_amdgcn_mfma_f32_16x16x32_f16(
              af[mi], bf[ni], acc[mi][ni], 0, 0, 0);
    }
    __syncthreads();
  }

#pragma unroll
  for (int ni = 0; ni < 4; ++ni) {
    const int c = n0 + ni * 16 + ln;
    const float bias_c = bo[c];
#pragma unroll
    for (int mi = 0; mi < 2; ++mi) {
      const int mb = m0 + w * 32 + mi * 16 + quad * 4;
#pragma unroll
      for (int r = 0; r < 4; ++r)
        out[(size_t)(mb + r) * DM + c] = acc[mi][ni][r] + bias_c;
    }
  }
}

// ---------------------------- flash attention ------------------------------
// R19: 1024 blocks x 2 waves (128 thr); block = (bh = i&31, qb = 31-(i>>5),
// 64 q-rows, longest first). Wave e takes kv tiles t == e (mod 2); exactly
// qb+1 tiles each. Per tile: K,V global->reg (8 x dwordx4), then per
// q-subtile qs (16 rows): 4 QK MFMA -> exp2+mask -> Ps (LDS, slot-swizzled)
// -> 4 PV MFMA. 32 MFMA per 8KB K/V = 4x intensity of R13-R18. No staging,
// no barriers in the loop; one syncthreads + LDS parity-merge per block.

template <int MODE>   // 0: full | 1: diag(qs0,1)+full(qs2,3) | 2: skip+diag
__device__ __forceinline__ void tile64(
    const _Float16* __restrict__ kb_, const _Float16* __restrict__ vb_,
    int t, const f16x8 (&qf)[4][2], f32x4 (&oacc)[4][4], float (&l_i)[4],
    _Float16* Ps, int quad, int ln, int l)
{
  f16x8 kr[4], vr[4];
#pragma unroll
  for (int ii = 0; ii < 4; ++ii)
    kr[ii] = *(const f16x8*)(kb_ + (size_t)t * 2048 + ii * 512 + l * 8);
#pragma unroll
  for (int ii = 0; ii < 4; ++ii)
    vr[ii] = *(const f16x8*)(vb_ + (size_t)t * 2048 + ii * 512 + l * 8);

  const f32x4 z4 = {0.f, 0.f, 0.f, 0.f};
#pragma unroll
  for (int qs = 0; qs < 4; ++qs) {
    if (MODE == 2 && qs < 2) continue;   // empty sub-tiles above diagonal

    f32x4 sacc[2];
    sacc[0] = z4; sacc[1] = z4;
#pragma unroll
    for (int ks = 0; ks < 2; ++ks)
#pragma unroll
      for (int mi = 0; mi < 2; ++mi)
        sacc[mi] = __builtin_amdgcn_mfma_f32_16x16x32_f16(
            kr[mi * 2 + ks], qf[qs][ks], sacc[mi], 0, 0, 0);

    const bool DG = (MODE == 1 && qs < 2) || (MODE == 2);
    const int hq = ((MODE == 1) ? qs : (qs - 2)) << 4;

    float rs = 0.f;
#pragma unroll
    for (int mi = 0; mi < 2; ++mi) {
      float p[4];
#pragma unroll
      for (int r = 0; r < 4; ++r) {
        p[r] = __builtin_amdgcn_exp2f(sacc[mi][r]);
        if (DG && (mi * 16 + quad * 4 + r > hq + ln)) p[r] = 0.f;
        rs += p[r];
      }
      const f16x2 lo = pkrtz(p[0], p[1]);
      const f16x2 hi = pkrtz(p[2], p[3]);
      const f16x4 pk = __builtin_shufflevector(lo, hi, 0, 1, 2, 3);
      // slot swizzle: stride 64 halfs (128 B) -> row drops out of bank index
      const int slot = ((mi * 4 + quad) + 2 * ln) & 15;
      *(f16x4*)&Ps[ln * 64 + slot * 4] = pk;
    }
    l_i[qs] += rs;

    const int slot2 = ((quad * 2) + 2 * ln) & 15;  // even -> 16B aligned
    const f16x8 pb = *(const f16x8*)&Ps[ln * 64 + slot2 * 4];

#pragma unroll
    for (int di = 0; di < 4; ++di)
      oacc[qs][di] = __builtin_amdgcn_mfma_f32_16x16x32_f16(
          vr[di], pb, oacc[qs][di], 0, 0, 0);
  }
}

__global__ __launch_bounds__(128, 3) void attn_kernel(
    const _Float16* __restrict__ QF, const _Float16* __restrict__ KF,
    const _Float16* __restrict__ VF, _Float16* __restrict__ Ob)
{
  __shared__ _Float16 Ps[2][1024];      // 4 KB (2 KB per wave)
  __shared__ float mrgO[4][1024];       // 16 KB: [qs][di*256 + l*4]
  __shared__ float mrgL[4][64];         // 1 KB

  const int i = blockIdx.x;
  const int bh = i & 31;                // heads XCD-local
  const int qb = 31 - (i >> 5);         // 64-row q-block; longest first

  const int tid = threadIdx.x;
  const int e = tid >> 6, l = tid & 63; // e = kv parity
  const int quad = l >> 4, ln = l & 15;

  const _Float16* qb_ = QF + (size_t)bh * 131072;
  const _Float16* kb_ = KF + (size_t)bh * 131072;
  const _Float16* vb_ = VF + (size_t)bh * 131072;
  _Float16* psw = &Ps[e][0];
  const int bidx = bh >> 4, hh = bh & 15;

  // Q fragments for rows [qb*64, +64): row-block rb = 4*qb + qs
  f16x8 qf[4][2];
#pragma unroll
  for (int qs = 0; qs < 4; ++qs)
#pragma unroll
    for (int ks = 0; ks < 2; ++ks)
      qf[qs][ks] = *(const f16x8*)
          (qb_ + (size_t)((4 * qb + qs) * 2 + ks) * 512 + l * 8);

  const f32x4 z4 = {0.f, 0.f, 0.f, 0.f};
  f32x4 oacc[4][4];
#pragma unroll
  for (int qs = 0; qs < 4; ++qs)
#pragma unroll
    for (int di = 0; di < 4; ++di) oacc[qs][di] = z4;
  float l_i[4] = {0.f, 0.f, 0.f, 0.f};

  int t = e;
  for (; t < 2 * qb; t += 2)
    tile64<0>(kb_, vb_, t, qf, oacc, l_i, psw, quad, ln, l);
  if (e == 0)
    tile64<1>(kb_, vb_, 2 * qb, qf, oacc, l_i, psw, quad, ln, l);
  else
    tile64<2>(kb_, vb_, 2 * qb + 1, qf, oacc, l_i, psw, quad, ln, l);

  // parity merge: wave 1 writes, barrier, wave 0 adds + outputs
  if (e) {
#pragma unroll
    for (int qs = 0; qs < 4; ++qs) {
#pragma unroll
      for (int di = 0; di < 4; ++di)
        *(f32x4*)&mrgO[qs][di * 256 + l * 4] = oacc[qs][di];
      mrgL[qs][l] = l_i[qs];
    }
  }
  __syncthreads();
  if (!e) {
#pragma unroll
    for (int qs = 0; qs < 4; ++qs) {
#pragma unroll
      for (int di = 0; di < 4; ++di)
        oacc[qs][di] += *(const f32x4*)&mrgO[qs][di * 256 + l * 4];
      float li = l_i[qs] + mrgL[qs][l];
      li += __shfl_xor(li, 16);
      li += __shfl_xor(li, 32);
      const float inv = 1.0f / li;

      const int q = qb * 64 + qs * 16 + ln;
      _Float16* orow = Ob + (size_t)(bidx * S_ + q) * DM + hh * DH + quad * 4;
#pragma unroll
      for (int di = 0; di < 4; ++di) {
        f16x4 o4;
#pragma unroll
        for (int r = 0; r < 4; ++r)
          o4[r] = (_Float16)(oacc[qs][di][r] * inv);
        *(f16x4*)(orow + di * 16) = o4;
      }
    }
  }
}

// ------------------------------- launcher ----------------------------------

extern "C" void kernel_launch(void* const* d_in, const int* in_sizes, int n_in,
                              void* d_out, int out_size, void* d_ws, size_t ws_size,
                              hipStream_t stream) {
  (void)in_sizes; (void)n_in; (void)out_size; (void)ws_size;
  const float* x  = (const float*)d_in[0];
  const float* Wq = (const float*)d_in[1];
  const float* bq = (const float*)d_in[2];
  const float* Wk = (const float*)d_in[3];
  const float* bk = (const float*)d_in[4];
  const float* Wv = (const float*)d_in[5];
  const float* bv = (const float*)d_in[6];
  const float* Wo = (const float*)d_in[7];
  const float* bo = (const float*)d_in[8];

  char* ws = (char*)d_ws;
  _Float16* xb  = (_Float16*)(ws);                      // 8 MB
  _Float16* wb  = (_Float16*)(ws + (8u << 20));         // 4 x 2 MB
  _Float16* qkv = (_Float16*)(ws + (16u << 20));        // QF,KF,VF 8 MB each
  _Float16* ob  = (_Float16*)(ws + (40u << 20));        // 8 MB

  cvt_all_kernel<<<dim3(8192), dim3(256), 0, stream>>>(x, Wq, Wk, Wv, Wo, xb, wb);
  gemm_qkv_kernel<<<dim3(8, 32, 3), dim3(256), 0, stream>>>(xb, wb, bq, bk, bv, qkv);
  attn_kernel<<<dim3(1024), dim3(128), 0, stream>>>(
      qkv, qkv + 4194304, qkv + 2 * 4194304, ob);
  gemm_out_kernel<<<dim3(16, 32), dim3(256), 0, stream>>>(
      ob, wb + (size_t)3 * DM * DM, bo, (float*)d_out);
}

// Round 8
// 180.199 us; speedup vs baseline: 1.0341x; 1.0089x over previous
//
#include <hip/hip_runtime.h>

// ---------------------------------------------------------------------------
// StandardMultiHeadAttention: B=2, S=2048, D=1024, H=16, Dh=64, causal.
// fp32->f16 convert -> QKV GEMM (XCD-partitioned, single-generation) ->
// flash attention (64 q-rows/wave, K/V global->reg) -> output GEMM
// (XCD-partitioned).
//
// Workspace (48 MB):
//   [0,8M)    xb : x f16 [4096,1024]
//   [8M,16M)  wb : Wq,Wk,Wv,Wo f16 (row=out, K-major)
//   [16M,24M) QF : Q frag-major (pre-scaled by 0.125*log2e)
//   [24M,32M) KF : K frag-major (tile-contiguous, 2048 halfs / 32-row tile)
//   [32M,40M) VF : V^T frag-major (same tiling)
//   [40M,48M) ob : attention output [B,S,1024] f16
//
// R20 accounting across R2-R19: non-attn time is a constant ~142us; ~88us
// of it is harness re-poison fills (2 x 44us, 256MiB WRITE_SIZE) inside the
// timed region. Controllable: attn ~40, qkv ~34, out ~12-20, cvt ~8.
// R20 theory: GEMMs are HBM/L2-locality bound. Old qkv grid (8,32,3) put
// the 8 n-panels sharing an A-panel on 8 DIFFERENT XCDs -> each XCD
// re-streams all 8MB of xb per z (~192MB fetch ~ 31us). Fix: 1-D grid,
// xcd = i&7 owns m-panels [4*xcd, 4*xcd+4) for ALL (n,z) -> A-lines fetched
// once per XCD, hit by 24 co-resident sharers (k-synchronized since single
// generation). qkv: launch_bounds(256,3), 768 blocks = exactly 3/CU (no
// tail generation; LDS 32KB x 3 = 96KB ok, ~116 VGPR < 170 cap).
// gemm_out same treatment: xcd owns 4 m-panels for all 16 n (fetch 128MB
// -> ~24MB). Attn (R19) and cvt untouched.
// ---------------------------------------------------------------------------

typedef _Float16 f16x8 __attribute__((ext_vector_type(8)));
typedef _Float16 f16x4 __attribute__((ext_vector_type(4)));
typedef _Float16 f16x2 __attribute__((ext_vector_type(2)));
typedef float f32x4 __attribute__((ext_vector_type(4)));

#define S_  2048
#define DM  1024
#define NH  16
#define DH  64

__device__ __forceinline__ void gload_lds16(const void* g, void* s) {
  __builtin_amdgcn_global_load_lds(
      (const __attribute__((address_space(1))) void*)g,
      (__attribute__((address_space(3))) void*)s, 16, 0, 0);
}

__device__ __forceinline__ f16x2 pkrtz(float a, float b) {
  return __builtin_bit_cast(f16x2, __builtin_amdgcn_cvt_pkrtz(a, b));
}

// ----------------------------- convert kernel ------------------------------
// blocks [0,4096): x -> xb ; blocks [4096,8192): Wq..Wo -> wb

__global__ void cvt_all_kernel(const float* __restrict__ x,
                               const float* __restrict__ w0,
                               const float* __restrict__ w1,
                               const float* __restrict__ w2,
                               const float* __restrict__ w3,
                               _Float16* __restrict__ xb,
                               _Float16* __restrict__ wb) {
  const int bid = blockIdx.x;
  const float* src;
  _Float16* dst;
  int idx;
  if (bid < 4096) {
    src = x; dst = xb; idx = bid * 256 + threadIdx.x;
  } else {
    const int j = bid - 4096;
    const int y = j >> 10;
    src = (y == 0) ? w0 : (y == 1) ? w1 : (y == 2) ? w2 : w3;
    dst = wb + (size_t)y * (DM * DM);
    idx = (j & 1023) * 256 + threadIdx.x;
  }
  const float4 v = ((const float4*)src)[idx];
  f16x4 h;
  h[0] = (_Float16)v.x; h[1] = (_Float16)v.y;
  h[2] = (_Float16)v.z; h[3] = (_Float16)v.w;
  ((f16x4*)dst)[idx] = h;
}

// ---------------- QKV GEMM (BK=64, 2 slabs, XCD-partitioned) ----------------
// 1-D grid of 768. Decode: xcd = i&7, t = i>>3 (0..95):
//   m-panel = xcd*4 + (t&3)  (xcd owns 4 m-panels for all n,z)
//   u = t>>2 (0..23): n-panel = u&7, z = u>>3.
// z=0: Q (bias, *0.125*log2e, QF layout); z=1: K (KF); z=2: V (VF)

__global__ __launch_bounds__(256, 3) void gemm_qkv_kernel(
    const _Float16* __restrict__ xb, const _Float16* __restrict__ wb,
    const float* __restrict__ bq, const float* __restrict__ bk,
    const float* __restrict__ bv, _Float16* __restrict__ qkv)
{
  __shared__ _Float16 As[2][128 * 32];   // slab h: k in [k0+32h, k0+32h+32)
  __shared__ _Float16 Ws[2][128 * 32];

  const int i = blockIdx.x;
  const int xcd = i & 7;
  const int tt = i >> 3;                 // 0..95
  const int mp = xcd * 4 + (tt & 3);     // m-panel 0..31
  const int u = tt >> 2;                 // 0..23
  const int np = u & 7;                  // n-panel 0..7
  const int z = u >> 3;                  // projection 0..2

  const _Float16* W = wb + (size_t)z * (DM * DM);
  const float* bias = (z == 0) ? bq : ((z == 1) ? bk : bv);
  _Float16* out = qkv + (size_t)z * 4194304;

  const f32x4 z4 = {0.f, 0.f, 0.f, 0.f};
  f32x4 acc[4][4];
#pragma unroll
  for (int mi = 0; mi < 4; ++mi)
#pragma unroll
    for (int ni = 0; ni < 4; ++ni) acc[mi][ni] = z4;

  const int m0 = mp * 128, n0 = np * 128;
  const int t = threadIdx.x;
  const int w = t >> 6, l = t & 63;
  const int quad = l >> 4, ln = l & 15;
  const int wm = (w >> 1) << 6, wn = (w & 1) << 6;
  const int srow = l >> 2, scol = (l & 3) << 3;

  for (int k0 = 0; k0 < DM; k0 += 64) {
#pragma unroll
    for (int h = 0; h < 2; ++h)
#pragma unroll
      for (int i2 = 0; i2 < 2; ++i2) {
        const int ra = w * 32 + i2 * 16;
        gload_lds16(&xb[(size_t)(m0 + ra + srow) * DM + k0 + h * 32 + scol],
                    &As[h][ra * 32]);
        gload_lds16(&W[(size_t)(n0 + ra + srow) * DM + k0 + h * 32 + scol],
                    &Ws[h][ra * 32]);
      }
    __syncthreads();

#pragma unroll
    for (int h = 0; h < 2; ++h) {
      f16x8 af[4], bf[4];
#pragma unroll
      for (int mi = 0; mi < 4; ++mi)
        af[mi] = *(const f16x8*)&As[h][(wm + mi * 16 + ln) * 32 + quad * 8];
#pragma unroll
      for (int ni = 0; ni < 4; ++ni)
        bf[ni] = *(const f16x8*)&Ws[h][(wn + ni * 16 + ln) * 32 + quad * 8];
#pragma unroll
      for (int mi = 0; mi < 4; ++mi)
#pragma unroll
        for (int ni = 0; ni < 4; ++ni)
          acc[mi][ni] = __builtin_amdgcn_mfma_f32_16x16x32_f16(
              af[mi], bf[ni], acc[mi][ni], 0, 0, 0);
    }
    __syncthreads();
  }

  // fold 1/sqrt(Dh) * log2(e) into Q so attention uses exp2
  const float scale = (z == 0) ? 0.18033688f : 1.0f;

#pragma unroll
  for (int ni = 0; ni < 4; ++ni) {
    const int c = n0 + wn + ni * 16 + ln;
    const float bias_c = bias[c];
    const int h = c >> 6, d = c & 63;
#pragma unroll
    for (int mi = 0; mi < 4; ++mi) {
      const int mb = m0 + wm + mi * 16 + quad * 4;
#pragma unroll
      for (int r = 0; r < 4; ++r) {
        const int mg = mb + r;
        const int b = mg >> 11, s = mg & 2047;
        const int bh = b * NH + h;
        const float v = (acc[mi][ni][r] + bias_c) * scale;
        size_t idx;
        if (z == 2)
          idx = (size_t)bh * 131072 + (s >> 5) * 2048 + (d >> 4) * 512 +
                ((s >> 3) & 3) * 128 + (d & 15) * 8 + (s & 7);
        else
          idx = (size_t)bh * 131072 + (s >> 4) * 1024 + (d >> 5) * 512 +
                ((d >> 3) & 3) * 128 + (s & 15) * 8 + (d & 7);
        out[idx] = (_Float16)v;
      }
    }
  }
}

// -------- output GEMM (BK=64 two-slab, 128x64 tile, XCD-partitioned) --------
// 1-D grid of 512. Decode: xcd = i&7, t = i>>3 (0..63):
//   m-panel = xcd*4 + (t&3); n-panel = t>>2 (0..15).

__global__ __launch_bounds__(256, 2) void gemm_out_kernel(
    const _Float16* __restrict__ ob, const _Float16* __restrict__ wo,
    const float* __restrict__ bo, float* __restrict__ out)
{
  __shared__ _Float16 As[2][128 * 32];
  __shared__ _Float16 Ws[2][64 * 32];

  const int i = blockIdx.x;
  const int xcd = i & 7;
  const int tt = i >> 3;                 // 0..63
  const int mp = xcd * 4 + (tt & 3);     // m-panel 0..31
  const int np = tt >> 2;                // n-panel 0..15

  const f32x4 z4 = {0.f, 0.f, 0.f, 0.f};
  f32x4 acc[2][4];
#pragma unroll
  for (int mi = 0; mi < 2; ++mi)
#pragma unroll
    for (int ni = 0; ni < 4; ++ni) acc[mi][ni] = z4;

  const int m0 = mp * 128, n0 = np * 64;
  const int t = threadIdx.x;
  const int w = t >> 6, l = t & 63;
  const int quad = l >> 4, ln = l & 15;
  const int srow = l >> 2, scol = (l & 3) << 3;

  for (int k0 = 0; k0 < DM; k0 += 64) {
#pragma unroll
    for (int h = 0; h < 2; ++h) {
#pragma unroll
      for (int i2 = 0; i2 < 2; ++i2) {
        const int ra = w * 32 + i2 * 16;
        gload_lds16(&ob[(size_t)(m0 + ra + srow) * DM + k0 + h * 32 + scol],
                    &As[h][ra * 32]);
      }
      gload_lds16(&wo[(size_t)(n0 + w * 16 + srow) * DM + k0 + h * 32 + scol],
                  &Ws[h][w * 16 * 32]);
    }
    __syncthreads();

#pragma unroll
    for (int h = 0; h < 2; ++h) {
      f16x8 af[2], bf[4];
#pragma unroll
      for (int mi = 0; mi < 2; ++mi)
        af[mi] = *(const f16x8*)&As[h][(w * 32 + mi * 16 + ln) * 32 + quad * 8];
#pragma unroll
      for (int ni = 0; ni < 4; ++ni)
        bf[ni] = *(const f16x8*)&Ws[h][(ni * 16 + ln) * 32 + quad * 8];
#pragma unroll
      for (int mi = 0; mi < 2; ++mi)
#pragma unroll
        for (int ni = 0; ni < 4; ++ni)
          acc[mi][ni] = __builtin_amdgcn_mfma_f32_16x16x32_f16(
              af[mi], bf[ni], acc[mi][ni], 0, 0, 0);
    }
    __syncthreads();
  }

#pragma unroll
  for (int ni = 0; ni < 4; ++ni) {
    const int c = n0 + ni * 16 + ln;
    const float bias_c = bo[c];
#pragma unroll
    for (int mi = 0; mi < 2; ++mi) {
      const int mb = m0 + w * 32 + mi * 16 + quad * 4;
#pragma unroll
      for (int r = 0; r < 4; ++r)
        out[(size_t)(mb + r) * DM + c] = acc[mi][ni][r] + bias_c;
    }
  }
}

// ---------------------------- flash attention ------------------------------
// R19: 1024 blocks x 2 waves (128 thr); block = (bh = i&31, qb = 31-(i>>5),
// 64 q-rows, longest first). Wave e takes kv tiles t == e (mod 2); exactly
// qb+1 tiles each. Per tile: K,V global->reg (8 x dwordx4), then per
// q-subtile qs (16 rows): 4 QK MFMA -> exp2+mask -> Ps (LDS, slot-swizzled)
// -> 4 PV MFMA. 32 MFMA per 8KB K/V = 4x intensity of R13-R18. No staging,
// no barriers in the loop; one syncthreads + LDS parity-merge per block.

template <int MODE>   // 0: full | 1: diag(qs0,1)+full(qs2,3) | 2: skip+diag
__device__ __forceinline__ void tile64(
    const _Float16* __restrict__ kb_, const _Float16* __restrict__ vb_,
    int t, const f16x8 (&qf)[4][2], f32x4 (&oacc)[4][4], float (&l_i)[4],
    _Float16* Ps, int quad, int ln, int l)
{
  f16x8 kr[4], vr[4];
#pragma unroll
  for (int ii = 0; ii < 4; ++ii)
    kr[ii] = *(const f16x8*)(kb_ + (size_t)t * 2048 + ii * 512 + l * 8);
#pragma unroll
  for (int ii = 0; ii < 4; ++ii)
    vr[ii] = *(const f16x8*)(vb_ + (size_t)t * 2048 + ii * 512 + l * 8);

  const f32x4 z4 = {0.f, 0.f, 0.f, 0.f};
#pragma unroll
  for (int qs = 0; qs < 4; ++qs) {
    if (MODE == 2 && qs < 2) continue;   // empty sub-tiles above diagonal

    f32x4 sacc[2];
    sacc[0] = z4; sacc[1] = z4;
#pragma unroll
    for (int ks = 0; ks < 2; ++ks)
#pragma unroll
      for (int mi = 0; mi < 2; ++mi)
        sacc[mi] = __builtin_amdgcn_mfma_f32_16x16x32_f16(
            kr[mi * 2 + ks], qf[qs][ks], sacc[mi], 0, 0, 0);

    const bool DG = (MODE == 1 && qs < 2) || (MODE == 2);
    const int hq = ((MODE == 1) ? qs : (qs - 2)) << 4;

    float rs = 0.f;
#pragma unroll
    for (int mi = 0; mi < 2; ++mi) {
      float p[4];
#pragma unroll
      for (int r = 0; r < 4; ++r) {
        p[r] = __builtin_amdgcn_exp2f(sacc[mi][r]);
        if (DG && (mi * 16 + quad * 4 + r > hq + ln)) p[r] = 0.f;
        rs += p[r];
      }
      const f16x2 lo = pkrtz(p[0], p[1]);
      const f16x2 hi = pkrtz(p[2], p[3]);
      const f16x4 pk = __builtin_shufflevector(lo, hi, 0, 1, 2, 3);
      // slot swizzle: stride 64 halfs (128 B) -> row drops out of bank index
      const int slot = ((mi * 4 + quad) + 2 * ln) & 15;
      *(f16x4*)&Ps[ln * 64 + slot * 4] = pk;
    }
    l_i[qs] += rs;

    const int slot2 = ((quad * 2) + 2 * ln) & 15;  // even -> 16B aligned
    const f16x8 pb = *(const f16x8*)&Ps[ln * 64 + slot2 * 4];

#pragma unroll
    for (int di = 0; di < 4; ++di)
      oacc[qs][di] = __builtin_amdgcn_mfma_f32_16x16x32_f16(
          vr[di], pb, oacc[qs][di], 0, 0, 0);
  }
}

__global__ __launch_bounds__(128, 3) void attn_kernel(
    const _Float16* __restrict__ QF, const _Float16* __restrict__ KF,
    const _Float16* __restrict__ VF, _Float16* __restrict__ Ob)
{
  __shared__ _Float16 Ps[2][1024];      // 4 KB (2 KB per wave)
  __shared__ float mrgO[4][1024];       // 16 KB: [qs][di*256 + l*4]
  __shared__ float mrgL[4][64];         // 1 KB

  const int i = blockIdx.x;
  const int bh = i & 31;                // heads XCD-local
  const int qb = 31 - (i >> 5);         // 64-row q-block; longest first

  const int tid = threadIdx.x;
  const int e = tid >> 6, l = tid & 63; // e = kv parity
  const int quad = l >> 4, ln = l & 15;

  const _Float16* qb_ = QF + (size_t)bh * 131072;
  const _Float16* kb_ = KF + (size_t)bh * 131072;
  const _Float16* vb_ = VF + (size_t)bh * 131072;
  _Float16* psw = &Ps[e][0];
  const int bidx = bh >> 4, hh = bh & 15;

  // Q fragments for rows [qb*64, +64): row-block rb = 4*qb + qs
  f16x8 qf[4][2];
#pragma unroll
  for (int qs = 0; qs < 4; ++qs)
#pragma unroll
    for (int ks = 0; ks < 2; ++ks)
      qf[qs][ks] = *(const f16x8*)
          (qb_ + (size_t)((4 * qb + qs) * 2 + ks) * 512 + l * 8);

  const f32x4 z4 = {0.f, 0.f, 0.f, 0.f};
  f32x4 oacc[4][4];
#pragma unroll
  for (int qs = 0; qs < 4; ++qs)
#pragma unroll
    for (int di = 0; di < 4; ++di) oacc[qs][di] = z4;
  float l_i[4] = {0.f, 0.f, 0.f, 0.f};

  int t = e;
  for (; t < 2 * qb; t += 2)
    tile64<0>(kb_, vb_, t, qf, oacc, l_i, psw, quad, ln, l);
  if (e == 0)
    tile64<1>(kb_, vb_, 2 * qb, qf, oacc, l_i, psw, quad, ln, l);
  else
    tile64<2>(kb_, vb_, 2 * qb + 1, qf, oacc, l_i, psw, quad, ln, l);

  // parity merge: wave 1 writes, barrier, wave 0 adds + outputs
  if (e) {
#pragma unroll
    for (int qs = 0; qs < 4; ++qs) {
#pragma unroll
      for (int di = 0; di < 4; ++di)
        *(f32x4*)&mrgO[qs][di * 256 + l * 4] = oacc[qs][di];
      mrgL[qs][l] = l_i[qs];
    }
  }
  __syncthreads();
  if (!e) {
#pragma unroll
    for (int qs = 0; qs < 4; ++qs) {
#pragma unroll
      for (int di = 0; di < 4; ++di)
        oacc[qs][di] += *(const f32x4*)&mrgO[qs][di * 256 + l * 4];
      float li = l_i[qs] + mrgL[qs][l];
      li += __shfl_xor(li, 16);
      li += __shfl_xor(li, 32);
      const float inv = 1.0f / li;

      const int q = qb * 64 + qs * 16 + ln;
      _Float16* orow = Ob + (size_t)(bidx * S_ + q) * DM + hh * DH + quad * 4;
#pragma unroll
      for (int di = 0; di < 4; ++di) {
        f16x4 o4;
#pragma unroll
        for (int r = 0; r < 4; ++r)
          o4[r] = (_Float16)(oacc[qs][di][r] * inv);
        *(f16x4*)(orow + di * 16) = o4;
      }
    }
  }
}

// ------------------------------- launcher ----------------------------------

extern "C" void kernel_launch(void* const* d_in, const int* in_sizes, int n_in,
                              void* d_out, int out_size, void* d_ws, size_t ws_size,
                              hipStream_t stream) {
  (void)in_sizes; (void)n_in; (void)out_size; (void)ws_size;
  const float* x  = (const float*)d_in[0];
  const float* Wq = (const float*)d_in[1];
  const float* bq = (const float*)d_in[2];
  const float* Wk = (const float*)d_in[3];
  const float* bk = (const float*)d_in[4];
  const float* Wv = (const float*)d_in[5];
  const float* bv = (const float*)d_in[6];
  const float* Wo = (const float*)d_in[7];
  const float* bo = (const float*)d_in[8];

  char* ws = (char*)d_ws;
  _Float16* xb  = (_Float16*)(ws);                      // 8 MB
  _Float16* wb  = (_Float16*)(ws + (8u << 20));         // 4 x 2 MB
  _Float16* qkv = (_Float16*)(ws + (16u << 20));        // QF,KF,VF 8 MB each
  _Float16* ob  = (_Float16*)(ws + (40u << 20));        // 8 MB

  cvt_all_kernel<<<dim3(8192), dim3(256), 0, stream>>>(x, Wq, Wk, Wv, Wo, xb, wb);
  gemm_qkv_kernel<<<dim3(768), dim3(256), 0, stream>>>(xb, wb, bq, bk, bv, qkv);
  attn_kernel<<<dim3(1024), dim3(128), 0, stream>>>(
      qkv, qkv + 4194304, qkv + 2 * 4194304, ob);
  gemm_out_kernel<<<dim3(512), dim3(256), 0, stream>>>(
      ob, wb + (size_t)3 * DM * DM, bo, (float*)d_out);
}

// Round 9
// 172.543 us; speedup vs baseline: 1.0800x; 1.0444x over previous
//
#include <hip/hip_runtime.h>

// ---------------------------------------------------------------------------
// StandardMultiHeadAttention: B=2, S=2048, D=1024, H=16, Dh=64, causal.
// fp32->f16 convert -> QKV GEMM (XCD-partitioned) -> flash attention
// (64 q-rows/block, 4-way KV split, critical path 16 tiles) -> output GEMM
// (XCD-partitioned).
//
// Workspace (48 MB):
//   [0,8M)    xb : x f16 [4096,1024]
//   [8M,16M)  wb : Wq,Wk,Wv,Wo f16 (row=out, K-major)
//   [16M,24M) QF : Q frag-major (pre-scaled by 0.125*log2e)
//   [24M,32M) KF : K frag-major (tile-contiguous, 2048 halfs / 32-row tile)
//   [32M,40M) VF : V^T frag-major (same tiling)
//   [40M,48M) ob : attention output [B,S,1024] f16
//
// R21 theory (retrodicts R13-R19 all pinning at ~43us): the kernel makespan
// is the DIAGONAL BLOCK's serial tile chain. Every structure had a wave
// running 32 serial KV tiles (parity split of 64) at ~2700 cyc/chain
// (load-wait -> QK MFMA -> 32 exp2 -> pack -> LDS round-trip -> PV) = ~36us.
// Occupancy/VMEM/ILP changes moved throughput (12-16us side), never this
// path -> every null result explained, no saturated pipe ever visible.
// R21: 4-way KV split: 4 waves/block, wave e takes t == e (mod 4) ->
// critical path 16 tiles (~18-22us predicted). 2-round LDS merge tree
// (waves 1,3 write bufs; 0,2 add; 2 writes; 0 adds + outputs), 3 barriers.
// LDS 42KB -> 3 blocks/CU at launch_bounds(256,3) (~165 VGPR, 3 waves/SIMD).
// Same tiles, same traffic, same intensity -- only serial depth changes.
// ---------------------------------------------------------------------------

typedef _Float16 f16x8 __attribute__((ext_vector_type(8)));
typedef _Float16 f16x4 __attribute__((ext_vector_type(4)));
typedef _Float16 f16x2 __attribute__((ext_vector_type(2)));
typedef float f32x4 __attribute__((ext_vector_type(4)));

#define S_  2048
#define DM  1024
#define NH  16
#define DH  64

__device__ __forceinline__ void gload_lds16(const void* g, void* s) {
  __builtin_amdgcn_global_load_lds(
      (const __attribute__((address_space(1))) void*)g,
      (__attribute__((address_space(3))) void*)s, 16, 0, 0);
}

__device__ __forceinline__ f16x2 pkrtz(float a, float b) {
  return __builtin_bit_cast(f16x2, __builtin_amdgcn_cvt_pkrtz(a, b));
}

// ----------------------------- convert kernel ------------------------------
// blocks [0,4096): x -> xb ; blocks [4096,8192): Wq..Wo -> wb

__global__ void cvt_all_kernel(const float* __restrict__ x,
                               const float* __restrict__ w0,
                               const float* __restrict__ w1,
                               const float* __restrict__ w2,
                               const float* __restrict__ w3,
                               _Float16* __restrict__ xb,
                               _Float16* __restrict__ wb) {
  const int bid = blockIdx.x;
  const float* src;
  _Float16* dst;
  int idx;
  if (bid < 4096) {
    src = x; dst = xb; idx = bid * 256 + threadIdx.x;
  } else {
    const int j = bid - 4096;
    const int y = j >> 10;
    src = (y == 0) ? w0 : (y == 1) ? w1 : (y == 2) ? w2 : w3;
    dst = wb + (size_t)y * (DM * DM);
    idx = (j & 1023) * 256 + threadIdx.x;
  }
  const float4 v = ((const float4*)src)[idx];
  f16x4 h;
  h[0] = (_Float16)v.x; h[1] = (_Float16)v.y;
  h[2] = (_Float16)v.z; h[3] = (_Float16)v.w;
  ((f16x4*)dst)[idx] = h;
}

// ---------------- QKV GEMM (BK=64, 2 slabs, XCD-partitioned) ----------------
// 1-D grid of 768. Decode: xcd = i&7, t = i>>3 (0..95):
//   m-panel = xcd*4 + (t&3)  (xcd owns 4 m-panels for all n,z)
//   u = t>>2 (0..23): n-panel = u&7, z = u>>3.
// z=0: Q (bias, *0.125*log2e, QF layout); z=1: K (KF); z=2: V (VF)

__global__ __launch_bounds__(256, 3) void gemm_qkv_kernel(
    const _Float16* __restrict__ xb, const _Float16* __restrict__ wb,
    const float* __restrict__ bq, const float* __restrict__ bk,
    const float* __restrict__ bv, _Float16* __restrict__ qkv)
{
  __shared__ _Float16 As[2][128 * 32];   // slab h: k in [k0+32h, k0+32h+32)
  __shared__ _Float16 Ws[2][128 * 32];

  const int i = blockIdx.x;
  const int xcd = i & 7;
  const int tt = i >> 3;                 // 0..95
  const int mp = xcd * 4 + (tt & 3);     // m-panel 0..31
  const int u = tt >> 2;                 // 0..23
  const int np = u & 7;                  // n-panel 0..7
  const int z = u >> 3;                  // projection 0..2

  const _Float16* W = wb + (size_t)z * (DM * DM);
  const float* bias = (z == 0) ? bq : ((z == 1) ? bk : bv);
  _Float16* out = qkv + (size_t)z * 4194304;

  const f32x4 z4 = {0.f, 0.f, 0.f, 0.f};
  f32x4 acc[4][4];
#pragma unroll
  for (int mi = 0; mi < 4; ++mi)
#pragma unroll
    for (int ni = 0; ni < 4; ++ni) acc[mi][ni] = z4;

  const int m0 = mp * 128, n0 = np * 128;
  const int t = threadIdx.x;
  const int w = t >> 6, l = t & 63;
  const int quad = l >> 4, ln = l & 15;
  const int wm = (w >> 1) << 6, wn = (w & 1) << 6;
  const int srow = l >> 2, scol = (l & 3) << 3;

  for (int k0 = 0; k0 < DM; k0 += 64) {
#pragma unroll
    for (int h = 0; h < 2; ++h)
#pragma unroll
      for (int i2 = 0; i2 < 2; ++i2) {
        const int ra = w * 32 + i2 * 16;
        gload_lds16(&xb[(size_t)(m0 + ra + srow) * DM + k0 + h * 32 + scol],
                    &As[h][ra * 32]);
        gload_lds16(&W[(size_t)(n0 + ra + srow) * DM + k0 + h * 32 + scol],
                    &Ws[h][ra * 32]);
      }
    __syncthreads();

#pragma unroll
    for (int h = 0; h < 2; ++h) {
      f16x8 af[4], bf[4];
#pragma unroll
      for (int mi = 0; mi < 4; ++mi)
        af[mi] = *(const f16x8*)&As[h][(wm + mi * 16 + ln) * 32 + quad * 8];
#pragma unroll
      for (int ni = 0; ni < 4; ++ni)
        bf[ni] = *(const f16x8*)&Ws[h][(wn + ni * 16 + ln) * 32 + quad * 8];
#pragma unroll
      for (int mi = 0; mi < 4; ++mi)
#pragma unroll
        for (int ni = 0; ni < 4; ++ni)
          acc[mi][ni] = __builtin_amdgcn_mfma_f32_16x16x32_f16(
              af[mi], bf[ni], acc[mi][ni], 0, 0, 0);
    }
    __syncthreads();
  }

  // fold 1/sqrt(Dh) * log2(e) into Q so attention uses exp2
  const float scale = (z == 0) ? 0.18033688f : 1.0f;

#pragma unroll
  for (int ni = 0; ni < 4; ++ni) {
    const int c = n0 + wn + ni * 16 + ln;
    const float bias_c = bias[c];
    const int h = c >> 6, d = c & 63;
#pragma unroll
    for (int mi = 0; mi < 4; ++mi) {
      const int mb = m0 + wm + mi * 16 + quad * 4;
#pragma unroll
      for (int r = 0; r < 4; ++r) {
        const int mg = mb + r;
        const int b = mg >> 11, s = mg & 2047;
        const int bh = b * NH + h;
        const float v = (acc[mi][ni][r] + bias_c) * scale;
        size_t idx;
        if (z == 2)
          idx = (size_t)bh * 131072 + (s >> 5) * 2048 + (d >> 4) * 512 +
                ((s >> 3) & 3) * 128 + (d & 15) * 8 + (s & 7);
        else
          idx = (size_t)bh * 131072 + (s >> 4) * 1024 + (d >> 5) * 512 +
                ((d >> 3) & 3) * 128 + (s & 15) * 8 + (d & 7);
        out[idx] = (_Float16)v;
      }
    }
  }
}

// -------- output GEMM (BK=64 two-slab, 128x64 tile, XCD-partitioned) --------
// 1-D grid of 512. Decode: xcd = i&7, t = i>>3 (0..63):
//   m-panel = xcd*4 + (t&3); n-panel = t>>2 (0..15).

__global__ __launch_bounds__(256, 2) void gemm_out_kernel(
    const _Float16* __restrict__ ob, const _Float16* __restrict__ wo,
    const float* __restrict__ bo, float* __restrict__ out)
{
  __shared__ _Float16 As[2][128 * 32];
  __shared__ _Float16 Ws[2][64 * 32];

  const int i = blockIdx.x;
  const int xcd = i & 7;
  const int tt = i >> 3;                 // 0..63
  const int mp = xcd * 4 + (tt & 3);     // m-panel 0..31
  const int np = tt >> 2;                // n-panel 0..15

  const f32x4 z4 = {0.f, 0.f, 0.f, 0.f};
  f32x4 acc[2][4];
#pragma unroll
  for (int mi = 0; mi < 2; ++mi)
#pragma unroll
    for (int ni = 0; ni < 4; ++ni) acc[mi][ni] = z4;

  const int m0 = mp * 128, n0 = np * 64;
  const int t = threadIdx.x;
  const int w = t >> 6, l = t & 63;
  const int quad = l >> 4, ln = l & 15;
  const int srow = l >> 2, scol = (l & 3) << 3;

  for (int k0 = 0; k0 < DM; k0 += 64) {
#pragma unroll
    for (int h = 0; h < 2; ++h) {
#pragma unroll
      for (int i2 = 0; i2 < 2; ++i2) {
        const int ra = w * 32 + i2 * 16;
        gload_lds16(&ob[(size_t)(m0 + ra + srow) * DM + k0 + h * 32 + scol],
                    &As[h][ra * 32]);
      }
      gload_lds16(&wo[(size_t)(n0 + w * 16 + srow) * DM + k0 + h * 32 + scol],
                  &Ws[h][w * 16 * 32]);
    }
    __syncthreads();

#pragma unroll
    for (int h = 0; h < 2; ++h) {
      f16x8 af[2], bf[4];
#pragma unroll
      for (int mi = 0; mi < 2; ++mi)
        af[mi] = *(const f16x8*)&As[h][(w * 32 + mi * 16 + ln) * 32 + quad * 8];
#pragma unroll
      for (int ni = 0; ni < 4; ++ni)
        bf[ni] = *(const f16x8*)&Ws[h][(ni * 16 + ln) * 32 + quad * 8];
#pragma unroll
      for (int mi = 0; mi < 2; ++mi)
#pragma unroll
        for (int ni = 0; ni < 4; ++ni)
          acc[mi][ni] = __builtin_amdgcn_mfma_f32_16x16x32_f16(
              af[mi], bf[ni], acc[mi][ni], 0, 0, 0);
    }
    __syncthreads();
  }

#pragma unroll
  for (int ni = 0; ni < 4; ++ni) {
    const int c = n0 + ni * 16 + ln;
    const float bias_c = bo[c];
#pragma unroll
    for (int mi = 0; mi < 2; ++mi) {
      const int mb = m0 + w * 32 + mi * 16 + quad * 4;
#pragma unroll
      for (int r = 0; r < 4; ++r)
        out[(size_t)(mb + r) * DM + c] = acc[mi][ni][r] + bias_c;
    }
  }
}

// ---------------------------- flash attention ------------------------------
// R21: 1024 blocks x 4 waves (256 thr); block = (bh = i&31, qb = 31-(i>>5),
// 64 q-rows, longest first). Wave e takes kv tiles t == e (mod 4) ->
// critical path 16 serial tiles (was 32). Per tile: K,V global->reg, per
// q-subtile qs: 4 QK MFMA -> exp2+mask -> Ps (slot-swizzled) -> 4 PV MFMA.
// Merge tree: round 1: waves 1,3 write bufs 0,1; waves 0,2 add. round 2:
// wave 2 writes buf 0; wave 0 adds + outputs. 3 barriers/block.

template <int MODE>   // 0: full | 1: diag(qs0,1)+full(qs2,3) | 2: skip+diag
__device__ __forceinline__ void tile64(
    const _Float16* __restrict__ kb_, const _Float16* __restrict__ vb_,
    int t, const f16x8 (&qf)[4][2], f32x4 (&oacc)[4][4], float (&l_i)[4],
    _Float16* Ps, int quad, int ln, int l)
{
  f16x8 kr[4], vr[4];
#pragma unroll
  for (int ii = 0; ii < 4; ++ii)
    kr[ii] = *(const f16x8*)(kb_ + (size_t)t * 2048 + ii * 512 + l * 8);
#pragma unroll
  for (int ii = 0; ii < 4; ++ii)
    vr[ii] = *(const f16x8*)(vb_ + (size_t)t * 2048 + ii * 512 + l * 8);

  const f32x4 z4 = {0.f, 0.f, 0.f, 0.f};
#pragma unroll
  for (int qs = 0; qs < 4; ++qs) {
    if (MODE == 2 && qs < 2) continue;   // empty sub-tiles above diagonal

    f32x4 sacc[2];
    sacc[0] = z4; sacc[1] = z4;
#pragma unroll
    for (int ks = 0; ks < 2; ++ks)
#pragma unroll
      for (int mi = 0; mi < 2; ++mi)
        sacc[mi] = __builtin_amdgcn_mfma_f32_16x16x32_f16(
            kr[mi * 2 + ks], qf[qs][ks], sacc[mi], 0, 0, 0);

    const bool DG = (MODE == 1 && qs < 2) || (MODE == 2);
    const int hq = ((MODE == 1) ? qs : (qs - 2)) << 4;

    float rs = 0.f;
#pragma unroll
    for (int mi = 0; mi < 2; ++mi) {
      float p[4];
#pragma unroll
      for (int r = 0; r < 4; ++r) {
        p[r] = __builtin_amdgcn_exp2f(sacc[mi][r]);
        if (DG && (mi * 16 + quad * 4 + r > hq + ln)) p[r] = 0.f;
        rs += p[r];
      }
      const f16x2 lo = pkrtz(p[0], p[1]);
      const f16x2 hi = pkrtz(p[2], p[3]);
      const f16x4 pk = __builtin_shufflevector(lo, hi, 0, 1, 2, 3);
      // slot swizzle: stride 64 halfs (128 B) -> row drops out of bank index
      const int slot = ((mi * 4 + quad) + 2 * ln) & 15;
      *(f16x4*)&Ps[ln * 64 + slot * 4] = pk;
    }
    l_i[qs] += rs;

    const int slot2 = ((quad * 2) + 2 * ln) & 15;  // even -> 16B aligned
    const f16x8 pb = *(const f16x8*)&Ps[ln * 64 + slot2 * 4];

#pragma unroll
    for (int di = 0; di < 4; ++di)
      oacc[qs][di] = __builtin_amdgcn_mfma_f32_16x16x32_f16(
          vr[di], pb, oacc[qs][di], 0, 0, 0);
  }
}

__global__ __launch_bounds__(256, 3) void attn_kernel(
    const _Float16* __restrict__ QF, const _Float16* __restrict__ KF,
    const _Float16* __restrict__ VF, _Float16* __restrict__ Ob)
{
  __shared__ _Float16 Ps[4][1024];      // 8 KB (2 KB per wave)
  __shared__ float mrgO[2][4][1024];    // 32 KB: [buf][qs][di*256 + l*4]
  __shared__ float mrgL[2][4][64];      // 2 KB

  const int i = blockIdx.x;
  const int bh = i & 31;                // heads XCD-local
  const int qb = 31 - (i >> 5);         // 64-row q-block; longest first

  const int tid = threadIdx.x;
  const int e = tid >> 6, l = tid & 63; // e = kv residue class (mod 4)
  const int quad = l >> 4, ln = l & 15;

  const _Float16* qb_ = QF + (size_t)bh * 131072;
  const _Float16* kb_ = KF + (size_t)bh * 131072;
  const _Float16* vb_ = VF + (size_t)bh * 131072;
  _Float16* psw = &Ps[e][0];
  const int bidx = bh >> 4, hh = bh & 15;

  // Q fragments for rows [qb*64, +64): row-block rb = 4*qb + qs
  f16x8 qf[4][2];
#pragma unroll
  for (int qs = 0; qs < 4; ++qs)
#pragma unroll
    for (int ks = 0; ks < 2; ++ks)
      qf[qs][ks] = *(const f16x8*)
          (qb_ + (size_t)((4 * qb + qs) * 2 + ks) * 512 + l * 8);

  const f32x4 z4 = {0.f, 0.f, 0.f, 0.f};
  f32x4 oacc[4][4];
#pragma unroll
  for (int qs = 0; qs < 4; ++qs)
#pragma unroll
    for (int di = 0; di < 4; ++di) oacc[qs][di] = z4;
  float l_i[4] = {0.f, 0.f, 0.f, 0.f};

  // full tiles in this wave's residue class
  for (int t = e; t < 2 * qb; t += 4)
    tile64<0>(kb_, vb_, t, qf, oacc, l_i, psw, quad, ln, l);
  // diagonal tiles 2qb (MODE 1) and 2qb+1 (MODE 2), by residue class
  if (((2 * qb) & 3) == e)
    tile64<1>(kb_, vb_, 2 * qb, qf, oacc, l_i, psw, quad, ln, l);
  if (((2 * qb + 1) & 3) == e)
    tile64<2>(kb_, vb_, 2 * qb + 1, qf, oacc, l_i, psw, quad, ln, l);

  // merge round 1: waves 1,3 write bufs 0,1; waves 0,2 add
  if (e & 1) {
    const int buf = e >> 1;
#pragma unroll
    for (int qs = 0; qs < 4; ++qs) {
#pragma unroll
      for (int di = 0; di < 4; ++di)
        *(f32x4*)&mrgO[buf][qs][di * 256 + l * 4] = oacc[qs][di];
      mrgL[buf][qs][l] = l_i[qs];
    }
  }
  __syncthreads();
  if (!(e & 1)) {
    const int buf = e >> 1;
#pragma unroll
    for (int qs = 0; qs < 4; ++qs) {
#pragma unroll
      for (int di = 0; di < 4; ++di)
        oacc[qs][di] += *(const f32x4*)&mrgO[buf][qs][di * 256 + l * 4];
      l_i[qs] += mrgL[buf][qs][l];
    }
  }
  __syncthreads();   // WAR: round-1 reads done before buf 0 reuse
  // merge round 2: wave 2 writes buf 0; wave 0 adds + outputs
  if (e == 2) {
#pragma unroll
    for (int qs = 0; qs < 4; ++qs) {
#pragma unroll
      for (int di = 0; di < 4; ++di)
        *(f32x4*)&mrgO[0][qs][di * 256 + l * 4] = oacc[qs][di];
      mrgL[0][qs][l] = l_i[qs];
    }
  }
  __syncthreads();
  if (e == 0) {
#pragma unroll
    for (int qs = 0; qs < 4; ++qs) {
#pragma unroll
      for (int di = 0; di < 4; ++di)
        oacc[qs][di] += *(const f32x4*)&mrgO[0][qs][di * 256 + l * 4];
      float li = l_i[qs] + mrgL[0][qs][l];
      li += __shfl_xor(li, 16);
      li += __shfl_xor(li, 32);
      const float inv = 1.0f / li;

      const int q = qb * 64 + qs * 16 + ln;
      _Float16* orow = Ob + (size_t)(bidx * S_ + q) * DM + hh * DH + quad * 4;
#pragma unroll
      for (int di = 0; di < 4; ++di) {
        f16x4 o4;
#pragma unroll
        for (int r = 0; r < 4; ++r)
          o4[r] = (_Float16)(oacc[qs][di][r] * inv);
        *(f16x4*)(orow + di * 16) = o4;
      }
    }
  }
}

// ------------------------------- launcher ----------------------------------

extern "C" void kernel_launch(void* const* d_in, const int* in_sizes, int n_in,
                              void* d_out, int out_size, void* d_ws, size_t ws_size,
                              hipStream_t stream) {
  (void)in_sizes; (void)n_in; (void)out_size; (void)ws_size;
  const float* x  = (const float*)d_in[0];
  const float* Wq = (const float*)d_in[1];
  const float* bq = (const float*)d_in[2];
  const float* Wk = (const float*)d_in[3];
  const float* bk = (const float*)d_in[4];
  const float* Wv = (const float*)d_in[5];
  const float* bv = (const float*)d_in[6];
  const float* Wo = (const float*)d_in[7];
  const float* bo = (const float*)d_in[8];

  char* ws = (char*)d_ws;
  _Float16* xb  = (_Float16*)(ws);                      // 8 MB
  _Float16* wb  = (_Float16*)(ws + (8u << 20));         // 4 x 2 MB
  _Float16* qkv = (_Float16*)(ws + (16u << 20));        // QF,KF,VF 8 MB each
  _Float16* ob  = (_Float16*)(ws + (40u << 20));        // 8 MB

  cvt_all_kernel<<<dim3(8192), dim3(256), 0, stream>>>(x, Wq, Wk, Wv, Wo, xb, wb);
  gemm_qkv_kernel<<<dim3(768), dim3(256), 0, stream>>>(xb, wb, bq, bk, bv, qkv);
  attn_kernel<<<dim3(1024), dim3(256), 0, stream>>>(
      qkv, qkv + 4194304, qkv + 2 * 4194304, ob);
  gemm_out_kernel<<<dim3(512), dim3(256), 0, stream>>>(
      ob, wb + (size_t)3 * DM * DM, bo, (float*)d_out);
}